// Round 4
// baseline (2345.187 us; speedup 1.0000x reference)
//
#include <hip/hip_runtime.h>

// ---------------------------------------------------------------------------
// GCN: 3x GCNConv(9->16->16->16) + MLP(concat 25 ->128->128->1), N=250000,
// E=5,000,000 edges + self loops. f32 in/out; edge_index int32 OR int64
// (detected on device).
// Aggregation: bucket dst by high bits (128 nodes/bucket), scatter packed
// edges ((d&127)<<18 | s) into bucket-grouped order once, then per-layer
// LDS-atomic bucketed aggregation (no per-node CSR, no random 4B scatters).
// ---------------------------------------------------------------------------

__global__ __launch_bounds__(64) void k_detect(const void* __restrict__ edges,
                                               int* __restrict__ flag, int n_nodes)
{
    if (threadIdx.x == 0 && blockIdx.x == 0) {
        const long long* p = (const long long*)edges;
        int is64 = 1;
        for (int i = 0; i < 16; ++i) {
            long long v = p[i];
            if (v < 0 || v >= (long long)n_nodes) is64 = 0;
        }
        *flag = is64;
    }
}

// degi[d] += 1 over dst half of original edge array
__global__ __launch_bounds__(256) void k_hist(const void* __restrict__ edges,
                                              const int* __restrict__ flag,
                                              int* __restrict__ degi, long long E)
{
    long long i = (long long)blockIdx.x * 256 + threadIdx.x;
    if (i >= E) return;
    int d;
    if (*flag) d = (int)((const long long*)edges)[E + i];
    else       d = ((const int*)edges)[E + i];
    atomicAdd(&degi[d], 1);
}

// one wave per bucket: bcnt[b] = sum of degi over its 128 nodes
__global__ __launch_bounds__(256) void k_bucket_cnt(const int* __restrict__ degi,
                                                    int* __restrict__ bcnt,
                                                    int n, int NB)
{
    int wid = (blockIdx.x * 256 + threadIdx.x) >> 6;
    if (wid >= NB) return;
    int lane = threadIdx.x & 63;
    int base = wid << 7;
    int s = 0;
    int i0 = base + lane;      if (i0 < n) s += degi[i0];
    int i1 = base + 64 + lane; if (i1 < n) s += degi[i1];
#pragma unroll
    for (int off = 32; off > 0; off >>= 1) s += __shfl_xor(s, off);
    if (lane == 0) bcnt[wid] = s;
}

// single block exclusive scan in place over p[0..nb); writes total to p[nb]
__global__ __launch_bounds__(1024) void k_scan(int* __restrict__ p, int nb)
{
    __shared__ int s[1024];
    __shared__ int carry_s;
    int t = threadIdx.x;
    if (t == 0) carry_s = 0;
    __syncthreads();
    for (int base = 0; base < nb; base += 1024) {
        int idx = base + t;
        int v = (idx < nb) ? p[idx] : 0;
        s[t] = v;
        __syncthreads();
        for (int off = 1; off < 1024; off <<= 1) {
            int u = (t >= off) ? s[t - off] : 0;
            __syncthreads();
            s[t] += u;
            __syncthreads();
        }
        int carry = carry_s;
        if (idx < nb) p[idx] = carry + s[t] - v;
        __syncthreads();
        if (t == 0) carry_s += s[1023];
        __syncthreads();
    }
    if (t == 0) p[nb] = carry_s;
}

__global__ __launch_bounds__(256) void k_bcur_init(const int* __restrict__ boff,
                                                   int* __restrict__ bcur, int NB)
{
    int i = blockIdx.x * 256 + threadIdx.x;
    if (i < NB) bcur[i] = boff[i];
}

__global__ __launch_bounds__(256) void k_dinv(const int* __restrict__ degi,
                                              float* __restrict__ dinv, int n)
{
    int i = blockIdx.x * 256 + threadIdx.x;
    if (i < n) dinv[i] = rsqrtf((float)(degi[i] + 1));   // +1 self loop
}

// scatter packed edges into bucket-grouped order: epk[pos] = (d&127)<<18 | s
__global__ __launch_bounds__(256) void k_bscatter(const void* __restrict__ edges,
                                                  const int* __restrict__ flag,
                                                  int* __restrict__ bcur,
                                                  int* __restrict__ epk, long long E)
{
    long long i = (long long)blockIdx.x * 256 + threadIdx.x;
    if (i >= E) return;
    int s, d;
    if (*flag) {
        const long long* p = (const long long*)edges;
        s = (int)p[i]; d = (int)p[E + i];
    } else {
        const int* p = (const int*)edges;
        s = p[i]; d = p[E + i];
    }
    int pos = atomicAdd(&bcur[d >> 7], 1);
    epk[pos] = ((d & 127) << 18) | s;
}

// h = x @ W1 (9->16); hs = h * dinv
__global__ __launch_bounds__(256) void k_lin1(const float* __restrict__ x,
                                              const float* __restrict__ W1,
                                              const float* __restrict__ dinv,
                                              float* __restrict__ hs, int n)
{
    __shared__ float sW[144];
    if (threadIdx.x < 144) sW[threadIdx.x] = W1[threadIdx.x];
    __syncthreads();
    int i = blockIdx.x * 256 + threadIdx.x;
    if (i >= n) return;
    float xv[9];
#pragma unroll
    for (int k = 0; k < 9; ++k) xv[k] = x[(size_t)i * 9 + k];
    float di = dinv[i];
#pragma unroll
    for (int j = 0; j < 16; ++j) {
        float acc = 0.f;
#pragma unroll
        for (int k = 0; k < 9; ++k) acc = fmaf(xv[k], sW[k * 16 + j], acc);
        hs[(size_t)i * 16 + j] = acc * di;
    }
}

// t = relu(agg + bias); h = t @ W (16->16); hs = h * dinv
__global__ __launch_bounds__(256) void k_lin_mid(const float* __restrict__ bias,
                                                 const float* __restrict__ W,
                                                 const float* __restrict__ dinv,
                                                 const float* __restrict__ agg,
                                                 float* __restrict__ hs, int n)
{
    __shared__ float sW[256];
    __shared__ float sB[16];
    sW[threadIdx.x] = W[threadIdx.x];
    if (threadIdx.x < 16) sB[threadIdx.x] = bias[threadIdx.x];
    __syncthreads();
    int i = blockIdx.x * 256 + threadIdx.x;
    if (i >= n) return;
    float t[16];
#pragma unroll
    for (int k = 0; k < 16; ++k) {
        float v = agg[(size_t)i * 16 + k] + sB[k];
        t[k] = v > 0.f ? v : 0.f;
    }
    float di = dinv[i];
#pragma unroll
    for (int j = 0; j < 16; ++j) {
        float acc = 0.f;
#pragma unroll
        for (int k = 0; k < 16; ++k) acc = fmaf(t[k], sW[k * 16 + j], acc);
        hs[(size_t)i * 16 + j] = acc * di;
    }
}

// One block per bucket: LDS acc[128][16]; 16 edge slots x 16 feats.
// agg[d] = dinv[d] * (hs[d] + sum_{edges->d} hs[src])
__global__ __launch_bounds__(256) void k_gather_b(const int* __restrict__ epk,
                                                  const int* __restrict__ boff,
                                                  const float* __restrict__ dinv,
                                                  const float* __restrict__ hs,
                                                  float* __restrict__ agg, int n)
{
    __shared__ float acc[128 * 16];
    int b = blockIdx.x;
    int start = boff[b], end = boff[b + 1];
    int tid = threadIdx.x;
    for (int i = tid; i < 2048; i += 256) acc[i] = 0.f;
    __syncthreads();
    int slot = tid >> 4, k = tid & 15;
    for (int e = start + slot; e < end; e += 16) {
        int pk = epk[e];
        int s     = pk & 0x3FFFF;
        int local = pk >> 18;
        atomicAdd(&acc[local * 16 + k], hs[(size_t)s * 16 + k]);
    }
    __syncthreads();
    int nbase = b << 7;
    int limit = n - nbase; if (limit > 128) limit = 128;
    int total = limit * 16;
    size_t gbase = (size_t)nbase * 16;
    for (int i = tid; i < total; i += 256) {
        int node = nbase + (i >> 4);
        agg[gbase + i] = (acc[i] + hs[gbase + i]) * dinv[node];
    }
}

// MLP head: feat=[x(9),relu(agg3+b3)(16)]; z=relu(feat@Wl2+bl2);
// z2=relu(z@Wl3+bl3); out=z2@Wl4+bl4. 4 waves/block, 16-node tile per wave,
// weights from global (L1/L2), 40KB LDS -> 4 blocks/CU.
__global__ __launch_bounds__(256, 4) void k_mlp(const float* __restrict__ x,
                                                const float* __restrict__ agg3,
                                                const float* __restrict__ b3,
                                                const float* __restrict__ Wl2,
                                                const float* __restrict__ bl2,
                                                const float* __restrict__ Wl3,
                                                const float* __restrict__ bl3,
                                                const float* __restrict__ Wl4,
                                                const float* __restrict__ bl4,
                                                float* __restrict__ out, int n)
{
    __shared__ __align__(16) float zs[4][16][132];
    __shared__ __align__(16) float sfeat[4][16][28];

    int tid  = threadIdx.x;
    int w    = tid >> 6;
    int lane = tid & 63;
    int og   = lane & 15;
    int ng   = lane >> 4;
    int base = (blockIdx.x * 4 + w) * 16;

    for (int idx = lane; idx < 16 * 25; idx += 64) {
        int nn = idx / 25, f = idx - nn * 25;
        int node = base + nn;
        float v = 0.f;
        if (node < n) {
            if (f < 9) v = x[(size_t)node * 9 + f];
            else {
                float t = agg3[(size_t)node * 16 + (f - 9)] + b3[f - 9];
                v = t > 0.f ? t : 0.f;
            }
        }
        sfeat[w][nn][f] = v;
    }
    __syncthreads();

    float acc[4][8];
    {
        float4 b0 = *(const float4*)&bl2[og * 8];
        float4 b1 = *(const float4*)&bl2[og * 8 + 4];
#pragma unroll
        for (int i = 0; i < 4; ++i) {
            acc[i][0] = b0.x; acc[i][1] = b0.y; acc[i][2] = b0.z; acc[i][3] = b0.w;
            acc[i][4] = b1.x; acc[i][5] = b1.y; acc[i][6] = b1.z; acc[i][7] = b1.w;
        }
    }
#pragma unroll
    for (int k = 0; k < 25; ++k) {
        float4 w0 = *(const float4*)&Wl2[k * 128 + og * 8];
        float4 w1 = *(const float4*)&Wl2[k * 128 + og * 8 + 4];
#pragma unroll
        for (int i = 0; i < 4; ++i) {
            float f = sfeat[w][ng * 4 + i][k];
            acc[i][0] = fmaf(f, w0.x, acc[i][0]); acc[i][1] = fmaf(f, w0.y, acc[i][1]);
            acc[i][2] = fmaf(f, w0.z, acc[i][2]); acc[i][3] = fmaf(f, w0.w, acc[i][3]);
            acc[i][4] = fmaf(f, w1.x, acc[i][4]); acc[i][5] = fmaf(f, w1.y, acc[i][5]);
            acc[i][6] = fmaf(f, w1.z, acc[i][6]); acc[i][7] = fmaf(f, w1.w, acc[i][7]);
        }
    }
#pragma unroll
    for (int i = 0; i < 4; ++i) {
        float4 lo, hi;
        lo.x = acc[i][0] > 0.f ? acc[i][0] : 0.f; lo.y = acc[i][1] > 0.f ? acc[i][1] : 0.f;
        lo.z = acc[i][2] > 0.f ? acc[i][2] : 0.f; lo.w = acc[i][3] > 0.f ? acc[i][3] : 0.f;
        hi.x = acc[i][4] > 0.f ? acc[i][4] : 0.f; hi.y = acc[i][5] > 0.f ? acc[i][5] : 0.f;
        hi.z = acc[i][6] > 0.f ? acc[i][6] : 0.f; hi.w = acc[i][7] > 0.f ? acc[i][7] : 0.f;
        *(float4*)&zs[w][ng * 4 + i][og * 8]     = lo;
        *(float4*)&zs[w][ng * 4 + i][og * 8 + 4] = hi;
    }
    __syncthreads();

    {
        float4 b0 = *(const float4*)&bl3[og * 8];
        float4 b1 = *(const float4*)&bl3[og * 8 + 4];
#pragma unroll
        for (int i = 0; i < 4; ++i) {
            acc[i][0] = b0.x; acc[i][1] = b0.y; acc[i][2] = b0.z; acc[i][3] = b0.w;
            acc[i][4] = b1.x; acc[i][5] = b1.y; acc[i][6] = b1.z; acc[i][7] = b1.w;
        }
    }
#pragma unroll 2
    for (int k = 0; k < 128; ++k) {
        float4 w0 = *(const float4*)&Wl3[k * 128 + og * 8];
        float4 w1 = *(const float4*)&Wl3[k * 128 + og * 8 + 4];
#pragma unroll
        for (int i = 0; i < 4; ++i) {
            float z = zs[w][ng * 4 + i][k];
            acc[i][0] = fmaf(z, w0.x, acc[i][0]); acc[i][1] = fmaf(z, w0.y, acc[i][1]);
            acc[i][2] = fmaf(z, w0.z, acc[i][2]); acc[i][3] = fmaf(z, w0.w, acc[i][3]);
            acc[i][4] = fmaf(z, w1.x, acc[i][4]); acc[i][5] = fmaf(z, w1.y, acc[i][5]);
            acc[i][6] = fmaf(z, w1.z, acc[i][6]); acc[i][7] = fmaf(z, w1.w, acc[i][7]);
        }
    }

    {
        float4 w40 = *(const float4*)&Wl4[og * 8];
        float4 w41 = *(const float4*)&Wl4[og * 8 + 4];
        float bb = bl4[0];
#pragma unroll
        for (int i = 0; i < 4; ++i) {
            float p = 0.f;
            p = fmaf(acc[i][0] > 0.f ? acc[i][0] : 0.f, w40.x, p);
            p = fmaf(acc[i][1] > 0.f ? acc[i][1] : 0.f, w40.y, p);
            p = fmaf(acc[i][2] > 0.f ? acc[i][2] : 0.f, w40.z, p);
            p = fmaf(acc[i][3] > 0.f ? acc[i][3] : 0.f, w40.w, p);
            p = fmaf(acc[i][4] > 0.f ? acc[i][4] : 0.f, w41.x, p);
            p = fmaf(acc[i][5] > 0.f ? acc[i][5] : 0.f, w41.y, p);
            p = fmaf(acc[i][6] > 0.f ? acc[i][6] : 0.f, w41.z, p);
            p = fmaf(acc[i][7] > 0.f ? acc[i][7] : 0.f, w41.w, p);
            p += __shfl_xor(p, 1);
            p += __shfl_xor(p, 2);
            p += __shfl_xor(p, 4);
            p += __shfl_xor(p, 8);
            int node = base + ng * 4 + i;
            if (og == 0 && node < n) out[node] = p + bb;
        }
    }
}

extern "C" void kernel_launch(void* const* d_in, const int* in_sizes, int n_in,
                              void* d_out, int out_size, void* d_ws, size_t ws_size,
                              hipStream_t stream)
{
    const float* x   = (const float*)d_in[0];
    const void*  ei  = d_in[1];
    const float* W1  = (const float*)d_in[2];
    const float* b1  = (const float*)d_in[3];
    const float* W2  = (const float*)d_in[4];
    const float* b2  = (const float*)d_in[5];
    const float* W3  = (const float*)d_in[6];
    const float* b3  = (const float*)d_in[7];
    const float* Wl2 = (const float*)d_in[8];
    const float* bl2 = (const float*)d_in[9];
    const float* Wl3 = (const float*)d_in[10];
    const float* bl3 = (const float*)d_in[11];
    const float* Wl4 = (const float*)d_in[12];
    const float* bl4 = (const float*)d_in[13];
    float* out = (float*)d_out;

    int n        = in_sizes[0] / 9;          // 250000
    long long e2 = (long long)in_sizes[1];   // 2*E
    long long E  = e2 / 2;
    int NB       = (n + 127) >> 7;           // buckets of 128 nodes

    char* ws = (char*)d_ws;
    size_t off = 0;
    int*   flag = (int*)(ws + off); off += 256;
    int*   degi = (int*)(ws + off); off += (size_t)n * 4;        off = (off + 255) & ~(size_t)255;
    float* dinv = (float*)(ws + off); off += (size_t)n * 4;      off = (off + 255) & ~(size_t)255;
    int*   boff = (int*)(ws + off); off += (size_t)(NB + 1) * 4; off = (off + 255) & ~(size_t)255;
    int*   bcur = (int*)(ws + off); off += (size_t)NB * 4;       off = (off + 255) & ~(size_t)255;
    int*   epk  = (int*)(ws + off); off += (size_t)E * 4;        off = (off + 255) & ~(size_t)255;
    float* hs   = (float*)(ws + off); off += (size_t)n * 64;     off = (off + 255) & ~(size_t)255;
    float* agg  = (float*)(ws + off);

    int nb_n = (n + 255) / 256;
    int nb_e = (int)((E + 255) / 256);
    int nb_b = (NB + 3) / 4;      // one wave per bucket
    int nb_i = (NB + 255) / 256;

    k_detect<<<1, 64, 0, stream>>>(ei, flag, n);
    hipMemsetAsync(degi, 0, (size_t)n * 4, stream);
    k_hist<<<nb_e, 256, 0, stream>>>(ei, flag, degi, E);
    k_bucket_cnt<<<nb_b, 256, 0, stream>>>(degi, boff, n, NB);
    k_scan<<<1, 1024, 0, stream>>>(boff, NB);
    k_bcur_init<<<nb_i, 256, 0, stream>>>(boff, bcur, NB);
    k_dinv<<<nb_n, 256, 0, stream>>>(degi, dinv, n);
    k_bscatter<<<nb_e, 256, 0, stream>>>(ei, flag, bcur, epk, E);

    // layer 1
    k_lin1<<<nb_n, 256, 0, stream>>>(x, W1, dinv, hs, n);
    k_gather_b<<<NB, 256, 0, stream>>>(epk, boff, dinv, hs, agg, n);
    // layer 2
    k_lin_mid<<<nb_n, 256, 0, stream>>>(b1, W2, dinv, agg, hs, n);
    k_gather_b<<<NB, 256, 0, stream>>>(epk, boff, dinv, hs, agg, n);
    // layer 3
    k_lin_mid<<<nb_n, 256, 0, stream>>>(b2, W3, dinv, agg, hs, n);
    k_gather_b<<<NB, 256, 0, stream>>>(epk, boff, dinv, hs, agg, n);
    // MLP head
    k_mlp<<<(n + 63) / 64, 256, 0, stream>>>(x, agg, b3, Wl2, bl2, Wl3, bl3, Wl4, bl4,
                                             out, n);
}

// Round 5
// 1894.524 us; speedup vs baseline: 1.2379x; 1.2379x over previous
//
#include <hip/hip_runtime.h>

// ---------------------------------------------------------------------------
// GCN: 3x GCNConv(9->16->16->16) + MLP(concat 25 ->128->128->1), N=250000,
// E=5,000,000 edges + self loops. f32 in/out; edge_index int32 OR int64
// (detected on device).
// Aggregation: deterministic 2-pass binning into 512-node buckets with
// per-(bucket,block) 64B-aligned regions (single-writer lines -> no
// write-allocate amplification, zero global atomics), then per-layer
// LDS-atomic bucketed aggregation.
// ---------------------------------------------------------------------------

#define NBLK 512          // binning blocks (each owns a contiguous edge chunk)
#define BSH  9            // bucket shift: 512 nodes per bucket
#define BSZ  512
#define MAXNB 1024        // max buckets supported (n <= 524288)

__global__ __launch_bounds__(64) void k_detect(const void* __restrict__ edges,
                                               int* __restrict__ flag, int n_nodes)
{
    if (threadIdx.x == 0 && blockIdx.x == 0) {
        const long long* p = (const long long*)edges;
        int is64 = 1;
        for (int i = 0; i < 16; ++i) {
            long long v = p[i];
            if (v < 0 || v >= (long long)n_nodes) is64 = 0;
        }
        *flag = is64;
    }
}

// little-endian: low 32 bits of int64 value < 2^31 equal the int32 value
__device__ __forceinline__ int ld_idx(const void* edges, int f64, long long idx)
{
    return f64 ? ((const int*)edges)[idx << 1] : ((const int*)edges)[idx];
}

// per-block bucket histogram of dst; write rounded-to-16 counts bucket-major
__global__ __launch_bounds__(256) void k_hist2(const void* __restrict__ edges,
                                               const int* __restrict__ flag,
                                               int* __restrict__ cnt_blk,
                                               long long E, int NB)
{
    __shared__ int cnt[MAXNB];
    int tid = threadIdx.x;
    for (int b = tid; b < NB; b += 256) cnt[b] = 0;
    __syncthreads();
    int f64 = *flag;
    long long chunk = (E + NBLK - 1) / NBLK;
    long long lo = (long long)blockIdx.x * chunk;
    long long hi = lo + chunk; if (hi > E) hi = E;
    for (long long i = lo + tid; i < hi; i += 256) {
        int d = ld_idx(edges, f64, E + i);
        atomicAdd(&cnt[d >> BSH], 1);
    }
    __syncthreads();
    for (int b = tid; b < NB; b += 256)
        cnt_blk[(size_t)b * NBLK + blockIdx.x] = (cnt[b] + 15) & ~15;
}

// exclusive scan stage 1: per-256-chunk scan + per-block totals
__global__ __launch_bounds__(256) void k_scan1(const int* __restrict__ in,
                                               int* __restrict__ excl,
                                               int* __restrict__ partials, int n)
{
    __shared__ int s[256];
    int tid = threadIdx.x;
    int i = blockIdx.x * 256 + tid;
    int v = (i < n) ? in[i] : 0;
    s[tid] = v;
    __syncthreads();
#pragma unroll
    for (int off = 1; off < 256; off <<= 1) {
        int t = (tid >= off) ? s[tid - off] : 0;
        __syncthreads();
        s[tid] += t;
        __syncthreads();
    }
    if (i < n) excl[i] = s[tid] - v;
    if (tid == 255) partials[blockIdx.x] = s[255];
}

// stage 2: single block, exclusive scan of partials (carry loop)
__global__ __launch_bounds__(1024) void k_scan2(int* __restrict__ p, int nb)
{
    __shared__ int s[1024];
    __shared__ int carry_s;
    int t = threadIdx.x;
    if (t == 0) carry_s = 0;
    __syncthreads();
    for (int base = 0; base < nb; base += 1024) {
        int idx = base + t;
        int v = (idx < nb) ? p[idx] : 0;
        s[t] = v;
        __syncthreads();
        for (int off = 1; off < 1024; off <<= 1) {
            int u = (t >= off) ? s[t - off] : 0;
            __syncthreads();
            s[t] += u;
            __syncthreads();
        }
        int carry = carry_s;
        if (idx < nb) p[idx] = carry + s[t] - v;
        __syncthreads();
        if (t == 0) carry_s += s[1023];
        __syncthreads();
    }
}

// stage 3: add block offsets
__global__ __launch_bounds__(256) void k_scan3(int* __restrict__ excl,
                                               const int* __restrict__ partials, int n)
{
    int i = blockIdx.x * 256 + threadIdx.x;
    if (i < n) excl[i] += partials[blockIdx.x];
}

// re-histogram own chunk, read own bases, scatter packed edges into own
// 64B-aligned regions; sentinel-fill pad. Zero global atomics.
__global__ __launch_bounds__(256) void k_bin(const void* __restrict__ edges,
                                             const int* __restrict__ flag,
                                             const int* __restrict__ base_blk,
                                             int* __restrict__ epk,
                                             long long E, int NB)
{
    __shared__ int cnt[MAXNB];
    __shared__ int base[MAXNB];
    __shared__ int cur[MAXNB];
    int tid = threadIdx.x;
    for (int b = tid; b < NB; b += 256) cnt[b] = 0;
    __syncthreads();
    int f64 = *flag;
    long long chunk = (E + NBLK - 1) / NBLK;
    long long lo = (long long)blockIdx.x * chunk;
    long long hi = lo + chunk; if (hi > E) hi = E;
    for (long long i = lo + tid; i < hi; i += 256) {
        int d = ld_idx(edges, f64, E + i);
        atomicAdd(&cnt[d >> BSH], 1);
    }
    __syncthreads();
    for (int b = tid; b < NB; b += 256) {
        base[b] = base_blk[(size_t)b * NBLK + blockIdx.x];
        cur[b] = 0;
    }
    __syncthreads();
    for (long long i = lo + tid; i < hi; i += 256) {
        int s = ld_idx(edges, f64, i);
        int d = ld_idx(edges, f64, E + i);
        int b = d >> BSH;
        int slot = atomicAdd(&cur[b], 1);
        epk[base[b] + slot] = ((d & (BSZ - 1)) << 18) | s;
    }
    __syncthreads();
    for (int b = tid; b < NB; b += 256) {
        int c = cnt[b];
        int r = (c + 15) & ~15;
        for (int j = c; j < r; ++j) epk[base[b] + j] = -1;
    }
}

// per-bucket in-degree from binned edges -> dinv (fused rsqrt)
__global__ __launch_bounds__(256) void k_deg_dinv(const int* __restrict__ epk,
                                                  const int* __restrict__ base_blk,
                                                  float* __restrict__ dinv, int n)
{
    __shared__ int cnt[BSZ];
    int b = blockIdx.x;
    int tid = threadIdx.x;
    int start = base_blk[(size_t)b * NBLK];
    int end   = base_blk[(size_t)(b + 1) * NBLK];
    for (int i = tid; i < BSZ; i += 256) cnt[i] = 0;
    __syncthreads();
    for (int e = start + tid; e < end; e += 256) {
        int pk = epk[e];
        if (pk >= 0) atomicAdd(&cnt[pk >> 18], 1);
    }
    __syncthreads();
    int nbase = b << BSH;
    for (int l = tid; l < BSZ; l += 256) {
        int node = nbase + l;
        if (node < n) dinv[node] = rsqrtf((float)cnt[l] + 1.0f);
    }
}

// h = x @ W1 (9->16); hs = h * dinv
__global__ __launch_bounds__(256) void k_lin1(const float* __restrict__ x,
                                              const float* __restrict__ W1,
                                              const float* __restrict__ dinv,
                                              float* __restrict__ hs, int n)
{
    __shared__ float sW[144];
    if (threadIdx.x < 144) sW[threadIdx.x] = W1[threadIdx.x];
    __syncthreads();
    int i = blockIdx.x * 256 + threadIdx.x;
    if (i >= n) return;
    float xv[9];
#pragma unroll
    for (int k = 0; k < 9; ++k) xv[k] = x[(size_t)i * 9 + k];
    float di = dinv[i];
#pragma unroll
    for (int j = 0; j < 16; ++j) {
        float acc = 0.f;
#pragma unroll
        for (int k = 0; k < 9; ++k) acc = fmaf(xv[k], sW[k * 16 + j], acc);
        hs[(size_t)i * 16 + j] = acc * di;
    }
}

// t = relu(agg + bias); h = t @ W (16->16); hs = h * dinv
__global__ __launch_bounds__(256) void k_lin_mid(const float* __restrict__ bias,
                                                 const float* __restrict__ W,
                                                 const float* __restrict__ dinv,
                                                 const float* __restrict__ agg,
                                                 float* __restrict__ hs, int n)
{
    __shared__ float sW[256];
    __shared__ float sB[16];
    sW[threadIdx.x] = W[threadIdx.x];
    if (threadIdx.x < 16) sB[threadIdx.x] = bias[threadIdx.x];
    __syncthreads();
    int i = blockIdx.x * 256 + threadIdx.x;
    if (i >= n) return;
    float t[16];
#pragma unroll
    for (int k = 0; k < 16; ++k) {
        float v = agg[(size_t)i * 16 + k] + sB[k];
        t[k] = v > 0.f ? v : 0.f;
    }
    float di = dinv[i];
#pragma unroll
    for (int j = 0; j < 16; ++j) {
        float acc = 0.f;
#pragma unroll
        for (int k = 0; k < 16; ++k) acc = fmaf(t[k], sW[k * 16 + j], acc);
        hs[(size_t)i * 16 + j] = acc * di;
    }
}

// One block per bucket: LDS acc[512][16]; 16 edge slots x 16 feats.
// agg[d] = dinv[d] * (hs[d] + sum_{edges->d} hs[src])
__global__ __launch_bounds__(256) void k_gather_b(const int* __restrict__ epk,
                                                  const int* __restrict__ base_blk,
                                                  const float* __restrict__ dinv,
                                                  const float* __restrict__ hs,
                                                  float* __restrict__ agg, int n)
{
    __shared__ float acc[BSZ * 16];   // 32 KB
    int b = blockIdx.x;
    int tid = threadIdx.x;
    int start = base_blk[(size_t)b * NBLK];
    int end   = base_blk[(size_t)(b + 1) * NBLK];
    for (int i = tid; i < BSZ * 16; i += 256) acc[i] = 0.f;
    __syncthreads();
    int slot = tid >> 4, k = tid & 15;
    for (int e = start + slot; e < end; e += 16) {
        int pk = epk[e];
        if (pk < 0) continue;                       // sentinel pad
        int s     = pk & 0x3FFFF;
        int local = pk >> 18;
        atomicAdd(&acc[local * 16 + k], hs[(size_t)s * 16 + k]);
    }
    __syncthreads();
    int nbase = b << BSH;
    int limit = n - nbase; if (limit > BSZ) limit = BSZ;
    int total = limit * 16;
    size_t gbase = (size_t)nbase * 16;
    for (int i = tid; i < total; i += 256) {
        int node = nbase + (i >> 4);
        agg[gbase + i] = (acc[i] + hs[gbase + i]) * dinv[node];
    }
}

// MLP head: feat=[x(9),relu(agg3+b3)(16)]; z=relu(feat@Wl2+bl2);
// z2=relu(z@Wl3+bl3); out=z2@Wl4+bl4. 4 waves/block, 16-node tile per wave,
// weights from global (L1/L2), 40KB LDS -> 4 blocks/CU.
__global__ __launch_bounds__(256, 4) void k_mlp(const float* __restrict__ x,
                                                const float* __restrict__ agg3,
                                                const float* __restrict__ b3,
                                                const float* __restrict__ Wl2,
                                                const float* __restrict__ bl2,
                                                const float* __restrict__ Wl3,
                                                const float* __restrict__ bl3,
                                                const float* __restrict__ Wl4,
                                                const float* __restrict__ bl4,
                                                float* __restrict__ out, int n)
{
    __shared__ __align__(16) float zs[4][16][132];
    __shared__ __align__(16) float sfeat[4][16][28];

    int tid  = threadIdx.x;
    int w    = tid >> 6;
    int lane = tid & 63;
    int og   = lane & 15;
    int ng   = lane >> 4;
    int base = (blockIdx.x * 4 + w) * 16;

    for (int idx = lane; idx < 16 * 25; idx += 64) {
        int nn = idx / 25, f = idx - nn * 25;
        int node = base + nn;
        float v = 0.f;
        if (node < n) {
            if (f < 9) v = x[(size_t)node * 9 + f];
            else {
                float t = agg3[(size_t)node * 16 + (f - 9)] + b3[f - 9];
                v = t > 0.f ? t : 0.f;
            }
        }
        sfeat[w][nn][f] = v;
    }
    __syncthreads();

    float acc[4][8];
    {
        float4 b0 = *(const float4*)&bl2[og * 8];
        float4 b1 = *(const float4*)&bl2[og * 8 + 4];
#pragma unroll
        for (int i = 0; i < 4; ++i) {
            acc[i][0] = b0.x; acc[i][1] = b0.y; acc[i][2] = b0.z; acc[i][3] = b0.w;
            acc[i][4] = b1.x; acc[i][5] = b1.y; acc[i][6] = b1.z; acc[i][7] = b1.w;
        }
    }
#pragma unroll
    for (int k = 0; k < 25; ++k) {
        float4 w0 = *(const float4*)&Wl2[k * 128 + og * 8];
        float4 w1 = *(const float4*)&Wl2[k * 128 + og * 8 + 4];
#pragma unroll
        for (int i = 0; i < 4; ++i) {
            float f = sfeat[w][ng * 4 + i][k];
            acc[i][0] = fmaf(f, w0.x, acc[i][0]); acc[i][1] = fmaf(f, w0.y, acc[i][1]);
            acc[i][2] = fmaf(f, w0.z, acc[i][2]); acc[i][3] = fmaf(f, w0.w, acc[i][3]);
            acc[i][4] = fmaf(f, w1.x, acc[i][4]); acc[i][5] = fmaf(f, w1.y, acc[i][5]);
            acc[i][6] = fmaf(f, w1.z, acc[i][6]); acc[i][7] = fmaf(f, w1.w, acc[i][7]);
        }
    }
#pragma unroll
    for (int i = 0; i < 4; ++i) {
        float4 lo, hi;
        lo.x = acc[i][0] > 0.f ? acc[i][0] : 0.f; lo.y = acc[i][1] > 0.f ? acc[i][1] : 0.f;
        lo.z = acc[i][2] > 0.f ? acc[i][2] : 0.f; lo.w = acc[i][3] > 0.f ? acc[i][3] : 0.f;
        hi.x = acc[i][4] > 0.f ? acc[i][4] : 0.f; hi.y = acc[i][5] > 0.f ? acc[i][5] : 0.f;
        hi.z = acc[i][6] > 0.f ? acc[i][6] : 0.f; hi.w = acc[i][7] > 0.f ? acc[i][7] : 0.f;
        *(float4*)&zs[w][ng * 4 + i][og * 8]     = lo;
        *(float4*)&zs[w][ng * 4 + i][og * 8 + 4] = hi;
    }
    __syncthreads();

    {
        float4 b0 = *(const float4*)&bl3[og * 8];
        float4 b1 = *(const float4*)&bl3[og * 8 + 4];
#pragma unroll
        for (int i = 0; i < 4; ++i) {
            acc[i][0] = b0.x; acc[i][1] = b0.y; acc[i][2] = b0.z; acc[i][3] = b0.w;
            acc[i][4] = b1.x; acc[i][5] = b1.y; acc[i][6] = b1.z; acc[i][7] = b1.w;
        }
    }
#pragma unroll 2
    for (int k = 0; k < 128; ++k) {
        float4 w0 = *(const float4*)&Wl3[k * 128 + og * 8];
        float4 w1 = *(const float4*)&Wl3[k * 128 + og * 8 + 4];
#pragma unroll
        for (int i = 0; i < 4; ++i) {
            float z = zs[w][ng * 4 + i][k];
            acc[i][0] = fmaf(z, w0.x, acc[i][0]); acc[i][1] = fmaf(z, w0.y, acc[i][1]);
            acc[i][2] = fmaf(z, w0.z, acc[i][2]); acc[i][3] = fmaf(z, w0.w, acc[i][3]);
            acc[i][4] = fmaf(z, w1.x, acc[i][4]); acc[i][5] = fmaf(z, w1.y, acc[i][5]);
            acc[i][6] = fmaf(z, w1.z, acc[i][6]); acc[i][7] = fmaf(z, w1.w, acc[i][7]);
        }
    }

    {
        float4 w40 = *(const float4*)&Wl4[og * 8];
        float4 w41 = *(const float4*)&Wl4[og * 8 + 4];
        float bb = bl4[0];
#pragma unroll
        for (int i = 0; i < 4; ++i) {
            float p = 0.f;
            p = fmaf(acc[i][0] > 0.f ? acc[i][0] : 0.f, w40.x, p);
            p = fmaf(acc[i][1] > 0.f ? acc[i][1] : 0.f, w40.y, p);
            p = fmaf(acc[i][2] > 0.f ? acc[i][2] : 0.f, w40.z, p);
            p = fmaf(acc[i][3] > 0.f ? acc[i][3] : 0.f, w40.w, p);
            p = fmaf(acc[i][4] > 0.f ? acc[i][4] : 0.f, w41.x, p);
            p = fmaf(acc[i][5] > 0.f ? acc[i][5] : 0.f, w41.y, p);
            p = fmaf(acc[i][6] > 0.f ? acc[i][6] : 0.f, w41.z, p);
            p = fmaf(acc[i][7] > 0.f ? acc[i][7] : 0.f, w41.w, p);
            p += __shfl_xor(p, 1);
            p += __shfl_xor(p, 2);
            p += __shfl_xor(p, 4);
            p += __shfl_xor(p, 8);
            int node = base + ng * 4 + i;
            if (og == 0 && node < n) out[node] = p + bb;
        }
    }
}

extern "C" void kernel_launch(void* const* d_in, const int* in_sizes, int n_in,
                              void* d_out, int out_size, void* d_ws, size_t ws_size,
                              hipStream_t stream)
{
    const float* x   = (const float*)d_in[0];
    const void*  ei  = d_in[1];
    const float* W1  = (const float*)d_in[2];
    const float* b1  = (const float*)d_in[3];
    const float* W2  = (const float*)d_in[4];
    const float* b2  = (const float*)d_in[5];
    const float* W3  = (const float*)d_in[6];
    const float* b3  = (const float*)d_in[7];
    const float* Wl2 = (const float*)d_in[8];
    const float* bl2 = (const float*)d_in[9];
    const float* Wl3 = (const float*)d_in[10];
    const float* bl3 = (const float*)d_in[11];
    const float* Wl4 = (const float*)d_in[12];
    const float* bl4 = (const float*)d_in[13];
    float* out = (float*)d_out;

    int n        = in_sizes[0] / 9;          // 250000
    long long e2 = (long long)in_sizes[1];   // 2*E
    long long E  = e2 / 2;
    int NB       = (n + BSZ - 1) >> BSH;     // 489 buckets
    int L        = NB * NBLK + 1;            // scan length (extra slot = total)

    char* ws = (char*)d_ws;
    size_t off = 0;
    int*   flag     = (int*)(ws + off); off += 256;
    int*   cnt_blk  = (int*)(ws + off); off += (size_t)L * 4;        off = (off + 255) & ~(size_t)255;
    int*   base_blk = (int*)(ws + off); off += (size_t)L * 4;        off = (off + 255) & ~(size_t)255;
    int*   partials = (int*)(ws + off); off += 16384;
    float* dinv     = (float*)(ws + off); off += (size_t)n * 4;      off = (off + 255) & ~(size_t)255;
    int*   epk      = (int*)(ws + off); off += (E + (size_t)NBLK * NB * 16) * 4;
    off = (off + 255) & ~(size_t)255;
    float* hs       = (float*)(ws + off); off += (size_t)n * 64;     off = (off + 255) & ~(size_t)255;
    float* agg      = (float*)(ws + off);

    int nb_n = (n + 255) / 256;
    int nb_s = (L + 255) / 256;    // scan1/scan3 blocks (979)

    k_detect<<<1, 64, 0, stream>>>(ei, flag, n);
    hipMemsetAsync(cnt_blk + (L - 1), 0, 4, stream);   // extra slot -> total
    k_hist2<<<NBLK, 256, 0, stream>>>(ei, flag, cnt_blk, E, NB);
    k_scan1<<<nb_s, 256, 0, stream>>>(cnt_blk, base_blk, partials, L);
    k_scan2<<<1, 1024, 0, stream>>>(partials, nb_s);
    k_scan3<<<nb_s, 256, 0, stream>>>(base_blk, partials, L);
    k_bin<<<NBLK, 256, 0, stream>>>(ei, flag, base_blk, epk, E, NB);
    k_deg_dinv<<<NB, 256, 0, stream>>>(epk, base_blk, dinv, n);

    // layer 1
    k_lin1<<<nb_n, 256, 0, stream>>>(x, W1, dinv, hs, n);
    k_gather_b<<<NB, 256, 0, stream>>>(epk, base_blk, dinv, hs, agg, n);
    // layer 2
    k_lin_mid<<<nb_n, 256, 0, stream>>>(b1, W2, dinv, agg, hs, n);
    k_gather_b<<<NB, 256, 0, stream>>>(epk, base_blk, dinv, hs, agg, n);
    // layer 3
    k_lin_mid<<<nb_n, 256, 0, stream>>>(b2, W3, dinv, agg, hs, n);
    k_gather_b<<<NB, 256, 0, stream>>>(epk, base_blk, dinv, hs, agg, n);
    // MLP head
    k_mlp<<<(n + 63) / 64, 256, 0, stream>>>(x, agg, b3, Wl2, bl2, Wl3, bl3, Wl4, bl4,
                                             out, n);
}

// Round 6
// 636.572 us; speedup vs baseline: 3.6841x; 2.9761x over previous
//
#include <hip/hip_runtime.h>

// ---------------------------------------------------------------------------
// GCN: 3x GCNConv(9->16->16->16) + MLP(concat 25 ->128->128->1), N=250000,
// E=5,000,000 edges + self loops. f32 in/out; edge_index int32 OR int64
// (detected on device).
// Pipeline: deterministic 2-pass binning into 512-node buckets (single-writer
// 64B lines, zero global atomics) -> within-bucket counting sort to exact CSR
// (fused deg/dinv) -> per-node wave gather (16 slots x float4, high MLP) ->
// register-blocked MLP head.
// ---------------------------------------------------------------------------

#define NBLK 512          // binning blocks (each owns a contiguous edge chunk)
#define BSH  9            // bucket shift: 512 nodes per bucket
#define BSZ  512
#define MAXNB 1024        // max buckets supported (n <= 524288)

__global__ __launch_bounds__(64) void k_detect(const void* __restrict__ edges,
                                               int* __restrict__ flag, int n_nodes)
{
    if (threadIdx.x == 0 && blockIdx.x == 0) {
        const long long* p = (const long long*)edges;
        int is64 = 1;
        for (int i = 0; i < 16; ++i) {
            long long v = p[i];
            if (v < 0 || v >= (long long)n_nodes) is64 = 0;
        }
        *flag = is64;
    }
}

// little-endian: low 32 bits of int64 value < 2^31 equal the int32 value
__device__ __forceinline__ int ld_idx(const void* edges, int f64, long long idx)
{
    return f64 ? ((const int*)edges)[idx << 1] : ((const int*)edges)[idx];
}

// per-block bucket histogram of dst; write rounded-to-16 counts bucket-major
__global__ __launch_bounds__(256) void k_hist2(const void* __restrict__ edges,
                                               const int* __restrict__ flag,
                                               int* __restrict__ cnt_blk,
                                               long long E, int NB)
{
    __shared__ int cnt[MAXNB];
    int tid = threadIdx.x;
    for (int b = tid; b < NB; b += 256) cnt[b] = 0;
    __syncthreads();
    int f64 = *flag;
    long long chunk = (E + NBLK - 1) / NBLK;
    long long lo = (long long)blockIdx.x * chunk;
    long long hi = lo + chunk; if (hi > E) hi = E;
    for (long long i = lo + tid; i < hi; i += 256) {
        int d = ld_idx(edges, f64, E + i);
        atomicAdd(&cnt[d >> BSH], 1);
    }
    __syncthreads();
    for (int b = tid; b < NB; b += 256)
        cnt_blk[(size_t)b * NBLK + blockIdx.x] = (cnt[b] + 15) & ~15;
}

// exclusive scan stage 1
__global__ __launch_bounds__(256) void k_scan1(const int* __restrict__ in,
                                               int* __restrict__ excl,
                                               int* __restrict__ partials, int n)
{
    __shared__ int s[256];
    int tid = threadIdx.x;
    int i = blockIdx.x * 256 + tid;
    int v = (i < n) ? in[i] : 0;
    s[tid] = v;
    __syncthreads();
#pragma unroll
    for (int off = 1; off < 256; off <<= 1) {
        int t = (tid >= off) ? s[tid - off] : 0;
        __syncthreads();
        s[tid] += t;
        __syncthreads();
    }
    if (i < n) excl[i] = s[tid] - v;
    if (tid == 255) partials[blockIdx.x] = s[255];
}

// stage 2: single block, exclusive scan of partials (carry loop)
__global__ __launch_bounds__(1024) void k_scan2(int* __restrict__ p, int nb)
{
    __shared__ int s[1024];
    __shared__ int carry_s;
    int t = threadIdx.x;
    if (t == 0) carry_s = 0;
    __syncthreads();
    for (int base = 0; base < nb; base += 1024) {
        int idx = base + t;
        int v = (idx < nb) ? p[idx] : 0;
        s[t] = v;
        __syncthreads();
        for (int off = 1; off < 1024; off <<= 1) {
            int u = (t >= off) ? s[t - off] : 0;
            __syncthreads();
            s[t] += u;
            __syncthreads();
        }
        int carry = carry_s;
        if (idx < nb) p[idx] = carry + s[t] - v;
        __syncthreads();
        if (t == 0) carry_s += s[1023];
        __syncthreads();
    }
}

// stage 3: add block offsets
__global__ __launch_bounds__(256) void k_scan3(int* __restrict__ excl,
                                               const int* __restrict__ partials, int n)
{
    int i = blockIdx.x * 256 + threadIdx.x;
    if (i < n) excl[i] += partials[blockIdx.x];
}

// re-histogram own chunk, scatter packed edges into own 64B-aligned regions;
// sentinel-fill pad. Zero global atomics.
__global__ __launch_bounds__(256) void k_bin(const void* __restrict__ edges,
                                             const int* __restrict__ flag,
                                             const int* __restrict__ base_blk,
                                             int* __restrict__ epk,
                                             long long E, int NB)
{
    __shared__ int cnt[MAXNB];
    __shared__ int base[MAXNB];
    __shared__ int cur[MAXNB];
    int tid = threadIdx.x;
    for (int b = tid; b < NB; b += 256) cnt[b] = 0;
    __syncthreads();
    int f64 = *flag;
    long long chunk = (E + NBLK - 1) / NBLK;
    long long lo = (long long)blockIdx.x * chunk;
    long long hi = lo + chunk; if (hi > E) hi = E;
    for (long long i = lo + tid; i < hi; i += 256) {
        int d = ld_idx(edges, f64, E + i);
        atomicAdd(&cnt[d >> BSH], 1);
    }
    __syncthreads();
    for (int b = tid; b < NB; b += 256) {
        base[b] = base_blk[(size_t)b * NBLK + blockIdx.x];
        cur[b] = 0;
    }
    __syncthreads();
    for (long long i = lo + tid; i < hi; i += 256) {
        int s = ld_idx(edges, f64, i);
        int d = ld_idx(edges, f64, E + i);
        int b = d >> BSH;
        int slot = atomicAdd(&cur[b], 1);
        epk[base[b] + slot] = ((d & (BSZ - 1)) << 18) | s;
    }
    __syncthreads();
    for (int b = tid; b < NB; b += 256) {
        int c = cnt[b];
        int r = (c + 15) & ~15;
        for (int j = c; j < r; ++j) epk[base[b] + j] = -1;
    }
}

// within-bucket counting sort -> exact CSR; fused deg/dinv/row_off.
// One block of 256 per bucket. All scatter writes stay inside the bucket's
// exclusive contiguous region (single-writer cache lines).
__global__ __launch_bounds__(256) void k_csr(const int* __restrict__ epk,
                                             const int* __restrict__ base_blk,
                                             int* __restrict__ csr,
                                             int* __restrict__ row_off,
                                             int* __restrict__ degi,
                                             float* __restrict__ dinv, int n)
{
    __shared__ int cnt[BSZ];
    __shared__ int off[BSZ];
    __shared__ int ps[256];
    int b = blockIdx.x;
    int tid = threadIdx.x;
    int start = base_blk[(size_t)b * NBLK];
    int end   = base_blk[(size_t)(b + 1) * NBLK];
    cnt[tid] = 0; cnt[tid + 256] = 0;
    __syncthreads();
    for (int e = start + tid; e < end; e += 256) {
        int pk = epk[e];
        if (pk >= 0) atomicAdd(&cnt[pk >> 18], 1);
    }
    __syncthreads();
    int pairSum = cnt[2 * tid] + cnt[2 * tid + 1];
    ps[tid] = pairSum;
    __syncthreads();
#pragma unroll
    for (int o = 1; o < 256; o <<= 1) {
        int v = (tid >= o) ? ps[tid - o] : 0;
        __syncthreads();
        ps[tid] += v;
        __syncthreads();
    }
    int incl = ps[tid];
    off[2 * tid]     = incl - pairSum;
    off[2 * tid + 1] = incl - pairSum + cnt[2 * tid];
    __syncthreads();
    int nbase = b << BSH;
#pragma unroll
    for (int l = tid; l < BSZ; l += 256) {
        int node = nbase + l;
        if (node < n) {
            row_off[node] = start + off[l];
            degi[node]    = cnt[l];
            dinv[node]    = rsqrtf((float)cnt[l] + 1.0f);
        }
    }
    __syncthreads();
    for (int e = start + tid; e < end; e += 256) {
        int pk = epk[e];
        if (pk < 0) continue;
        int l = pk >> 18;
        int pos = atomicAdd(&off[l], 1);
        csr[start + pos] = pk & 0x3FFFF;
    }
}

// h = x @ W1 (9->16); hs = h * dinv
__global__ __launch_bounds__(256) void k_lin1(const float* __restrict__ x,
                                              const float* __restrict__ W1,
                                              const float* __restrict__ dinv,
                                              float* __restrict__ hs, int n)
{
    __shared__ float sW[144];
    if (threadIdx.x < 144) sW[threadIdx.x] = W1[threadIdx.x];
    __syncthreads();
    int i = blockIdx.x * 256 + threadIdx.x;
    if (i >= n) return;
    float xv[9];
#pragma unroll
    for (int k = 0; k < 9; ++k) xv[k] = x[(size_t)i * 9 + k];
    float di = dinv[i];
#pragma unroll
    for (int j = 0; j < 16; ++j) {
        float acc = 0.f;
#pragma unroll
        for (int k = 0; k < 9; ++k) acc = fmaf(xv[k], sW[k * 16 + j], acc);
        hs[(size_t)i * 16 + j] = acc * di;
    }
}

// t = relu(agg + bias); h = t @ W (16->16); hs = h * dinv
__global__ __launch_bounds__(256) void k_lin_mid(const float* __restrict__ bias,
                                                 const float* __restrict__ W,
                                                 const float* __restrict__ dinv,
                                                 const float* __restrict__ agg,
                                                 float* __restrict__ hs, int n)
{
    __shared__ float sW[256];
    __shared__ float sB[16];
    sW[threadIdx.x] = W[threadIdx.x];
    if (threadIdx.x < 16) sB[threadIdx.x] = bias[threadIdx.x];
    __syncthreads();
    int i = blockIdx.x * 256 + threadIdx.x;
    if (i >= n) return;
    float t[16];
#pragma unroll
    for (int k = 0; k < 16; ++k) {
        float v = agg[(size_t)i * 16 + k] + sB[k];
        t[k] = v > 0.f ? v : 0.f;
    }
    float di = dinv[i];
#pragma unroll
    for (int j = 0; j < 16; ++j) {
        float acc = 0.f;
#pragma unroll
        for (int k = 0; k < 16; ++k) acc = fmaf(t[k], sW[k * 16 + j], acc);
        hs[(size_t)i * 16 + j] = acc * di;
    }
}

// One wave per node, 16 edge-slots x 4 lanes (float4 each): 16 independent
// random 64B lines in flight per wave. agg[d]=dinv[d]*(hs[d]+sum hs[src]).
__global__ __launch_bounds__(256) void k_gather(const int* __restrict__ csr,
                                                const int* __restrict__ row_off,
                                                const int* __restrict__ degi,
                                                const float* __restrict__ dinv,
                                                const float* __restrict__ hs,
                                                float* __restrict__ agg, int n)
{
    int wid = (int)(((long long)blockIdx.x * 256 + threadIdx.x) >> 6);
    if (wid >= n) return;
    int lane = threadIdx.x & 63;
    int slot = lane >> 2;          // 16 slots
    int q    = lane & 3;           // float4 quarter of the 16-feature row
    int start = row_off[wid];
    int deg   = degi[wid];
    float4 sum;
    if (slot == 0) sum = *(const float4*)&hs[(size_t)wid * 16 + q * 4]; // self loop
    else           sum = make_float4(0.f, 0.f, 0.f, 0.f);
    for (int e = slot; e < deg; e += 16) {
        int s = csr[start + e];
        float4 v = *(const float4*)&hs[(size_t)s * 16 + q * 4];
        sum.x += v.x; sum.y += v.y; sum.z += v.z; sum.w += v.w;
    }
#pragma unroll
    for (int off = 4; off < 64; off <<= 1) {
        sum.x += __shfl_xor(sum.x, off);
        sum.y += __shfl_xor(sum.y, off);
        sum.z += __shfl_xor(sum.z, off);
        sum.w += __shfl_xor(sum.w, off);
    }
    if (slot == 0) {
        float di = dinv[wid];
        sum.x *= di; sum.y *= di; sum.z *= di; sum.w *= di;
        *(float4*)&agg[(size_t)wid * 16 + q * 4] = sum;
    }
}

// MLP head: feat=[x(9),relu(agg3+b3)(16)]; z=relu(feat@Wl2+bl2);
// z2=relu(z@Wl3+bl3); out=z2@Wl4+bl4. 4 waves/block, 16-node tile per wave,
// weights from global (L1/L2); k-loop split in 32KB halves for L1 residency.
__global__ __launch_bounds__(256, 4) void k_mlp(const float* __restrict__ x,
                                                const float* __restrict__ agg3,
                                                const float* __restrict__ b3,
                                                const float* __restrict__ Wl2,
                                                const float* __restrict__ bl2,
                                                const float* __restrict__ Wl3,
                                                const float* __restrict__ bl3,
                                                const float* __restrict__ Wl4,
                                                const float* __restrict__ bl4,
                                                float* __restrict__ out, int n)
{
    __shared__ __align__(16) float zs[4][16][132];
    __shared__ __align__(16) float sfeat[4][16][28];

    int tid  = threadIdx.x;
    int w    = tid >> 6;
    int lane = tid & 63;
    int og   = lane & 15;
    int ng   = lane >> 4;
    int base = (blockIdx.x * 4 + w) * 16;

    for (int idx = lane; idx < 16 * 25; idx += 64) {
        int nn = idx / 25, f = idx - nn * 25;
        int node = base + nn;
        float v = 0.f;
        if (node < n) {
            if (f < 9) v = x[(size_t)node * 9 + f];
            else {
                float t = agg3[(size_t)node * 16 + (f - 9)] + b3[f - 9];
                v = t > 0.f ? t : 0.f;
            }
        }
        sfeat[w][nn][f] = v;
    }
    __syncthreads();

    float acc[4][8];
    {
        float4 b0 = *(const float4*)&bl2[og * 8];
        float4 b1 = *(const float4*)&bl2[og * 8 + 4];
#pragma unroll
        for (int i = 0; i < 4; ++i) {
            acc[i][0] = b0.x; acc[i][1] = b0.y; acc[i][2] = b0.z; acc[i][3] = b0.w;
            acc[i][4] = b1.x; acc[i][5] = b1.y; acc[i][6] = b1.z; acc[i][7] = b1.w;
        }
    }
#pragma unroll
    for (int k = 0; k < 25; ++k) {
        float4 w0 = *(const float4*)&Wl2[k * 128 + og * 8];
        float4 w1 = *(const float4*)&Wl2[k * 128 + og * 8 + 4];
#pragma unroll
        for (int i = 0; i < 4; ++i) {
            float f = sfeat[w][ng * 4 + i][k];
            acc[i][0] = fmaf(f, w0.x, acc[i][0]); acc[i][1] = fmaf(f, w0.y, acc[i][1]);
            acc[i][2] = fmaf(f, w0.z, acc[i][2]); acc[i][3] = fmaf(f, w0.w, acc[i][3]);
            acc[i][4] = fmaf(f, w1.x, acc[i][4]); acc[i][5] = fmaf(f, w1.y, acc[i][5]);
            acc[i][6] = fmaf(f, w1.z, acc[i][6]); acc[i][7] = fmaf(f, w1.w, acc[i][7]);
        }
    }
#pragma unroll
    for (int i = 0; i < 4; ++i) {
        float4 lo, hi;
        lo.x = acc[i][0] > 0.f ? acc[i][0] : 0.f; lo.y = acc[i][1] > 0.f ? acc[i][1] : 0.f;
        lo.z = acc[i][2] > 0.f ? acc[i][2] : 0.f; lo.w = acc[i][3] > 0.f ? acc[i][3] : 0.f;
        hi.x = acc[i][4] > 0.f ? acc[i][4] : 0.f; hi.y = acc[i][5] > 0.f ? acc[i][5] : 0.f;
        hi.z = acc[i][6] > 0.f ? acc[i][6] : 0.f; hi.w = acc[i][7] > 0.f ? acc[i][7] : 0.f;
        *(float4*)&zs[w][ng * 4 + i][og * 8]     = lo;
        *(float4*)&zs[w][ng * 4 + i][og * 8 + 4] = hi;
    }
    __syncthreads();

    {
        float4 b0 = *(const float4*)&bl3[og * 8];
        float4 b1 = *(const float4*)&bl3[og * 8 + 4];
#pragma unroll
        for (int i = 0; i < 4; ++i) {
            acc[i][0] = b0.x; acc[i][1] = b0.y; acc[i][2] = b0.z; acc[i][3] = b0.w;
            acc[i][4] = b1.x; acc[i][5] = b1.y; acc[i][6] = b1.z; acc[i][7] = b1.w;
        }
    }
#pragma unroll 2
    for (int k = 0; k < 64; ++k) {
        float4 w0 = *(const float4*)&Wl3[k * 128 + og * 8];
        float4 w1 = *(const float4*)&Wl3[k * 128 + og * 8 + 4];
#pragma unroll
        for (int i = 0; i < 4; ++i) {
            float z = zs[w][ng * 4 + i][k];
            acc[i][0] = fmaf(z, w0.x, acc[i][0]); acc[i][1] = fmaf(z, w0.y, acc[i][1]);
            acc[i][2] = fmaf(z, w0.z, acc[i][2]); acc[i][3] = fmaf(z, w0.w, acc[i][3]);
            acc[i][4] = fmaf(z, w1.x, acc[i][4]); acc[i][5] = fmaf(z, w1.y, acc[i][5]);
            acc[i][6] = fmaf(z, w1.z, acc[i][6]); acc[i][7] = fmaf(z, w1.w, acc[i][7]);
        }
    }
    __syncthreads();    // keep all waves on the same 32KB half of Wl3 (L1)
#pragma unroll 2
    for (int k = 64; k < 128; ++k) {
        float4 w0 = *(const float4*)&Wl3[k * 128 + og * 8];
        float4 w1 = *(const float4*)&Wl3[k * 128 + og * 8 + 4];
#pragma unroll
        for (int i = 0; i < 4; ++i) {
            float z = zs[w][ng * 4 + i][k];
            acc[i][0] = fmaf(z, w0.x, acc[i][0]); acc[i][1] = fmaf(z, w0.y, acc[i][1]);
            acc[i][2] = fmaf(z, w0.z, acc[i][2]); acc[i][3] = fmaf(z, w0.w, acc[i][3]);
            acc[i][4] = fmaf(z, w1.x, acc[i][4]); acc[i][5] = fmaf(z, w1.y, acc[i][5]);
            acc[i][6] = fmaf(z, w1.z, acc[i][6]); acc[i][7] = fmaf(z, w1.w, acc[i][7]);
        }
    }

    {
        float4 w40 = *(const float4*)&Wl4[og * 8];
        float4 w41 = *(const float4*)&Wl4[og * 8 + 4];
        float bb = bl4[0];
#pragma unroll
        for (int i = 0; i < 4; ++i) {
            float p = 0.f;
            p = fmaf(acc[i][0] > 0.f ? acc[i][0] : 0.f, w40.x, p);
            p = fmaf(acc[i][1] > 0.f ? acc[i][1] : 0.f, w40.y, p);
            p = fmaf(acc[i][2] > 0.f ? acc[i][2] : 0.f, w40.z, p);
            p = fmaf(acc[i][3] > 0.f ? acc[i][3] : 0.f, w40.w, p);
            p = fmaf(acc[i][4] > 0.f ? acc[i][4] : 0.f, w41.x, p);
            p = fmaf(acc[i][5] > 0.f ? acc[i][5] : 0.f, w41.y, p);
            p = fmaf(acc[i][6] > 0.f ? acc[i][6] : 0.f, w41.z, p);
            p = fmaf(acc[i][7] > 0.f ? acc[i][7] : 0.f, w41.w, p);
            p += __shfl_xor(p, 1);
            p += __shfl_xor(p, 2);
            p += __shfl_xor(p, 4);
            p += __shfl_xor(p, 8);
            int node = base + ng * 4 + i;
            if (og == 0 && node < n) out[node] = p + bb;
        }
    }
}

extern "C" void kernel_launch(void* const* d_in, const int* in_sizes, int n_in,
                              void* d_out, int out_size, void* d_ws, size_t ws_size,
                              hipStream_t stream)
{
    const float* x   = (const float*)d_in[0];
    const void*  ei  = d_in[1];
    const float* W1  = (const float*)d_in[2];
    const float* b1  = (const float*)d_in[3];
    const float* W2  = (const float*)d_in[4];
    const float* b2  = (const float*)d_in[5];
    const float* W3  = (const float*)d_in[6];
    const float* b3  = (const float*)d_in[7];
    const float* Wl2 = (const float*)d_in[8];
    const float* bl2 = (const float*)d_in[9];
    const float* Wl3 = (const float*)d_in[10];
    const float* bl3 = (const float*)d_in[11];
    const float* Wl4 = (const float*)d_in[12];
    const float* bl4 = (const float*)d_in[13];
    float* out = (float*)d_out;

    int n        = in_sizes[0] / 9;          // 250000
    long long e2 = (long long)in_sizes[1];   // 2*E
    long long E  = e2 / 2;
    int NB       = (n + BSZ - 1) >> BSH;     // 489 buckets
    int L        = NB * NBLK + 1;            // scan length (extra slot = total)
    size_t EPAD  = (size_t)E + (size_t)NBLK * NB * 16;   // binned region elems

    char* ws = (char*)d_ws;
    size_t off = 0;
    int*   flag     = (int*)(ws + off); off += 256;
    int*   cnt_blk  = (int*)(ws + off); off += (size_t)L * 4;        off = (off + 255) & ~(size_t)255;
    int*   base_blk = (int*)(ws + off); off += (size_t)L * 4;        off = (off + 255) & ~(size_t)255;
    int*   partials = (int*)(ws + off); off += 16384;
    float* dinv     = (float*)(ws + off); off += (size_t)n * 4;      off = (off + 255) & ~(size_t)255;
    int*   degi     = (int*)(ws + off); off += (size_t)n * 4;        off = (off + 255) & ~(size_t)255;
    int*   row_off  = (int*)(ws + off); off += (size_t)n * 4;        off = (off + 255) & ~(size_t)255;
    int*   csr      = (int*)(ws + off); off += EPAD * 4;             off = (off + 255) & ~(size_t)255;
    int*   epk      = (int*)(ws + off); off += EPAD * 4;             off = (off + 255) & ~(size_t)255;
    // hs/agg alias epk (dead after k_csr); EPAD*4 = 36 MB >= 32 MB needed
    float* hs  = (float*)epk;
    float* agg = hs + (size_t)n * 16;

    int nb_n = (n + 255) / 256;
    int nb_s = (L + 255) / 256;

    k_detect<<<1, 64, 0, stream>>>(ei, flag, n);
    hipMemsetAsync(cnt_blk + (L - 1), 0, 4, stream);   // extra slot -> total
    k_hist2<<<NBLK, 256, 0, stream>>>(ei, flag, cnt_blk, E, NB);
    k_scan1<<<nb_s, 256, 0, stream>>>(cnt_blk, base_blk, partials, L);
    k_scan2<<<1, 1024, 0, stream>>>(partials, nb_s);
    k_scan3<<<nb_s, 256, 0, stream>>>(base_blk, partials, L);
    k_bin<<<NBLK, 256, 0, stream>>>(ei, flag, base_blk, epk, E, NB);
    k_csr<<<NB, 256, 0, stream>>>(epk, base_blk, csr, row_off, degi, dinv, n);

    int nb_g = (n + 3) / 4;   // one wave per node, 4 waves/block
    // layer 1
    k_lin1<<<nb_n, 256, 0, stream>>>(x, W1, dinv, hs, n);
    k_gather<<<nb_g, 256, 0, stream>>>(csr, row_off, degi, dinv, hs, agg, n);
    // layer 2
    k_lin_mid<<<nb_n, 256, 0, stream>>>(b1, W2, dinv, agg, hs, n);
    k_gather<<<nb_g, 256, 0, stream>>>(csr, row_off, degi, dinv, hs, agg, n);
    // layer 3
    k_lin_mid<<<nb_n, 256, 0, stream>>>(b2, W3, dinv, agg, hs, n);
    k_gather<<<nb_g, 256, 0, stream>>>(csr, row_off, degi, dinv, hs, agg, n);
    // MLP head
    k_mlp<<<(n + 63) / 64, 256, 0, stream>>>(x, agg, b3, Wl2, bl2, Wl3, bl3, Wl4, bl4,
                                             out, n);
}

// Round 7
// 615.500 us; speedup vs baseline: 3.8102x; 1.0342x over previous
//
#include <hip/hip_runtime.h>

// ---------------------------------------------------------------------------
// GCN: 3x GCNConv(9->16->16->16) + MLP(concat 25 ->128->128->1), N=250000,
// E=5,000,000 edges + self loops. f32 in/out; edge_index int32 OR int64
// (detected on device).
// Pipeline: deterministic 2-pass binning into 512-node buckets (single-writer
// 64B lines, zero global atomics) -> within-bucket counting sort to exact CSR
// (fused deg/dinv) -> per-node wave gather (16 slots x float4, high MLP) ->
// register-blocked MLP head.
// NOTE: k_mlp uses plain __launch_bounds__(256): any min-waves second arg
// makes the allocator cap at 64 VGPRs and spill the acc tile to scratch
// (observed r2/r5/r6: 190MB scratch traffic, 2-3x slowdown).
// ---------------------------------------------------------------------------

#define NBLK 512          // binning blocks (each owns a contiguous edge chunk)
#define BSH  9            // bucket shift: 512 nodes per bucket
#define BSZ  512
#define MAXNB 1024        // max buckets supported (n <= 524288)

__global__ __launch_bounds__(64) void k_detect(const void* __restrict__ edges,
                                               int* __restrict__ flag, int n_nodes)
{
    if (threadIdx.x == 0 && blockIdx.x == 0) {
        const long long* p = (const long long*)edges;
        int is64 = 1;
        for (int i = 0; i < 16; ++i) {
            long long v = p[i];
            if (v < 0 || v >= (long long)n_nodes) is64 = 0;
        }
        *flag = is64;
    }
}

// little-endian: low 32 bits of int64 value < 2^31 equal the int32 value
__device__ __forceinline__ int ld_idx(const void* edges, int f64, long long idx)
{
    return f64 ? ((const int*)edges)[idx << 1] : ((const int*)edges)[idx];
}

// per-block bucket histogram of dst; write rounded-to-16 counts bucket-major
__global__ __launch_bounds__(256) void k_hist2(const void* __restrict__ edges,
                                               const int* __restrict__ flag,
                                               int* __restrict__ cnt_blk,
                                               long long E, int NB)
{
    __shared__ int cnt[MAXNB];
    int tid = threadIdx.x;
    for (int b = tid; b < NB; b += 256) cnt[b] = 0;
    __syncthreads();
    int f64 = *flag;
    long long chunk = (E + NBLK - 1) / NBLK;
    long long lo = (long long)blockIdx.x * chunk;
    long long hi = lo + chunk; if (hi > E) hi = E;
    for (long long i = lo + tid; i < hi; i += 256) {
        int d = ld_idx(edges, f64, E + i);
        atomicAdd(&cnt[d >> BSH], 1);
    }
    __syncthreads();
    for (int b = tid; b < NB; b += 256)
        cnt_blk[(size_t)b * NBLK + blockIdx.x] = (cnt[b] + 15) & ~15;
}

// exclusive scan stage 1
__global__ __launch_bounds__(256) void k_scan1(const int* __restrict__ in,
                                               int* __restrict__ excl,
                                               int* __restrict__ partials, int n)
{
    __shared__ int s[256];
    int tid = threadIdx.x;
    int i = blockIdx.x * 256 + tid;
    int v = (i < n) ? in[i] : 0;
    s[tid] = v;
    __syncthreads();
#pragma unroll
    for (int off = 1; off < 256; off <<= 1) {
        int t = (tid >= off) ? s[tid - off] : 0;
        __syncthreads();
        s[tid] += t;
        __syncthreads();
    }
    if (i < n) excl[i] = s[tid] - v;
    if (tid == 255) partials[blockIdx.x] = s[255];
}

// stage 2: single block, exclusive scan of partials (carry loop)
__global__ __launch_bounds__(1024) void k_scan2(int* __restrict__ p, int nb)
{
    __shared__ int s[1024];
    __shared__ int carry_s;
    int t = threadIdx.x;
    if (t == 0) carry_s = 0;
    __syncthreads();
    for (int base = 0; base < nb; base += 1024) {
        int idx = base + t;
        int v = (idx < nb) ? p[idx] : 0;
        s[t] = v;
        __syncthreads();
        for (int off = 1; off < 1024; off <<= 1) {
            int u = (t >= off) ? s[t - off] : 0;
            __syncthreads();
            s[t] += u;
            __syncthreads();
        }
        int carry = carry_s;
        if (idx < nb) p[idx] = carry + s[t] - v;
        __syncthreads();
        if (t == 0) carry_s += s[1023];
        __syncthreads();
    }
}

// stage 3: add block offsets
__global__ __launch_bounds__(256) void k_scan3(int* __restrict__ excl,
                                               const int* __restrict__ partials, int n)
{
    int i = blockIdx.x * 256 + threadIdx.x;
    if (i < n) excl[i] += partials[blockIdx.x];
}

// re-histogram own chunk, scatter packed edges into own 64B-aligned regions;
// sentinel-fill pad. Zero global atomics.
__global__ __launch_bounds__(256) void k_bin(const void* __restrict__ edges,
                                             const int* __restrict__ flag,
                                             const int* __restrict__ base_blk,
                                             int* __restrict__ epk,
                                             long long E, int NB)
{
    __shared__ int cnt[MAXNB];
    __shared__ int base[MAXNB];
    __shared__ int cur[MAXNB];
    int tid = threadIdx.x;
    for (int b = tid; b < NB; b += 256) cnt[b] = 0;
    __syncthreads();
    int f64 = *flag;
    long long chunk = (E + NBLK - 1) / NBLK;
    long long lo = (long long)blockIdx.x * chunk;
    long long hi = lo + chunk; if (hi > E) hi = E;
    for (long long i = lo + tid; i < hi; i += 256) {
        int d = ld_idx(edges, f64, E + i);
        atomicAdd(&cnt[d >> BSH], 1);
    }
    __syncthreads();
    for (int b = tid; b < NB; b += 256) {
        base[b] = base_blk[(size_t)b * NBLK + blockIdx.x];
        cur[b] = 0;
    }
    __syncthreads();
    for (long long i = lo + tid; i < hi; i += 256) {
        int s = ld_idx(edges, f64, i);
        int d = ld_idx(edges, f64, E + i);
        int b = d >> BSH;
        int slot = atomicAdd(&cur[b], 1);
        epk[base[b] + slot] = ((d & (BSZ - 1)) << 18) | s;
    }
    __syncthreads();
    for (int b = tid; b < NB; b += 256) {
        int c = cnt[b];
        int r = (c + 15) & ~15;
        for (int j = c; j < r; ++j) epk[base[b] + j] = -1;
    }
}

// within-bucket counting sort -> exact CSR; fused deg/dinv/row_off.
__global__ __launch_bounds__(256) void k_csr(const int* __restrict__ epk,
                                             const int* __restrict__ base_blk,
                                             int* __restrict__ csr,
                                             int* __restrict__ row_off,
                                             int* __restrict__ degi,
                                             float* __restrict__ dinv, int n)
{
    __shared__ int cnt[BSZ];
    __shared__ int off[BSZ];
    __shared__ int ps[256];
    int b = blockIdx.x;
    int tid = threadIdx.x;
    int start = base_blk[(size_t)b * NBLK];
    int end   = base_blk[(size_t)(b + 1) * NBLK];
    cnt[tid] = 0; cnt[tid + 256] = 0;
    __syncthreads();
    for (int e = start + tid; e < end; e += 256) {
        int pk = epk[e];
        if (pk >= 0) atomicAdd(&cnt[pk >> 18], 1);
    }
    __syncthreads();
    int pairSum = cnt[2 * tid] + cnt[2 * tid + 1];
    ps[tid] = pairSum;
    __syncthreads();
#pragma unroll
    for (int o = 1; o < 256; o <<= 1) {
        int v = (tid >= o) ? ps[tid - o] : 0;
        __syncthreads();
        ps[tid] += v;
        __syncthreads();
    }
    int incl = ps[tid];
    off[2 * tid]     = incl - pairSum;
    off[2 * tid + 1] = incl - pairSum + cnt[2 * tid];
    __syncthreads();
    int nbase = b << BSH;
#pragma unroll
    for (int l = tid; l < BSZ; l += 256) {
        int node = nbase + l;
        if (node < n) {
            row_off[node] = start + off[l];
            degi[node]    = cnt[l];
            dinv[node]    = rsqrtf((float)cnt[l] + 1.0f);
        }
    }
    __syncthreads();
    for (int e = start + tid; e < end; e += 256) {
        int pk = epk[e];
        if (pk < 0) continue;
        int l = pk >> 18;
        int pos = atomicAdd(&off[l], 1);
        csr[start + pos] = pk & 0x3FFFF;
    }
}

// h = x @ W1 (9->16); hs = h * dinv
__global__ __launch_bounds__(256) void k_lin1(const float* __restrict__ x,
                                              const float* __restrict__ W1,
                                              const float* __restrict__ dinv,
                                              float* __restrict__ hs, int n)
{
    __shared__ float sW[144];
    if (threadIdx.x < 144) sW[threadIdx.x] = W1[threadIdx.x];
    __syncthreads();
    int i = blockIdx.x * 256 + threadIdx.x;
    if (i >= n) return;
    float xv[9];
#pragma unroll
    for (int k = 0; k < 9; ++k) xv[k] = x[(size_t)i * 9 + k];
    float di = dinv[i];
#pragma unroll
    for (int j = 0; j < 16; ++j) {
        float acc = 0.f;
#pragma unroll
        for (int k = 0; k < 9; ++k) acc = fmaf(xv[k], sW[k * 16 + j], acc);
        hs[(size_t)i * 16 + j] = acc * di;
    }
}

// t = relu(agg + bias); h = t @ W (16->16); hs = h * dinv
__global__ __launch_bounds__(256) void k_lin_mid(const float* __restrict__ bias,
                                                 const float* __restrict__ W,
                                                 const float* __restrict__ dinv,
                                                 const float* __restrict__ agg,
                                                 float* __restrict__ hs, int n)
{
    __shared__ float sW[256];
    __shared__ float sB[16];
    sW[threadIdx.x] = W[threadIdx.x];
    if (threadIdx.x < 16) sB[threadIdx.x] = bias[threadIdx.x];
    __syncthreads();
    int i = blockIdx.x * 256 + threadIdx.x;
    if (i >= n) return;
    float t[16];
#pragma unroll
    for (int k = 0; k < 16; ++k) {
        float v = agg[(size_t)i * 16 + k] + sB[k];
        t[k] = v > 0.f ? v : 0.f;
    }
    float di = dinv[i];
#pragma unroll
    for (int j = 0; j < 16; ++j) {
        float acc = 0.f;
#pragma unroll
        for (int k = 0; k < 16; ++k) acc = fmaf(t[k], sW[k * 16 + j], acc);
        hs[(size_t)i * 16 + j] = acc * di;
    }
}

// One wave per node, 16 edge-slots x 4 lanes (float4 each): 16 independent
// random 64B lines in flight per wave. agg[d]=dinv[d]*(hs[d]+sum hs[src]).
__global__ __launch_bounds__(256) void k_gather(const int* __restrict__ csr,
                                                const int* __restrict__ row_off,
                                                const int* __restrict__ degi,
                                                const float* __restrict__ dinv,
                                                const float* __restrict__ hs,
                                                float* __restrict__ agg, int n)
{
    int wid = (int)(((long long)blockIdx.x * 256 + threadIdx.x) >> 6);
    if (wid >= n) return;
    int lane = threadIdx.x & 63;
    int slot = lane >> 2;          // 16 slots
    int q    = lane & 3;           // float4 quarter of the 16-feature row
    int start = row_off[wid];
    int deg   = degi[wid];
    float4 sum;
    if (slot == 0) sum = *(const float4*)&hs[(size_t)wid * 16 + q * 4]; // self loop
    else           sum = make_float4(0.f, 0.f, 0.f, 0.f);
    for (int e = slot; e < deg; e += 16) {
        int s = csr[start + e];
        float4 v = *(const float4*)&hs[(size_t)s * 16 + q * 4];
        sum.x += v.x; sum.y += v.y; sum.z += v.z; sum.w += v.w;
    }
#pragma unroll
    for (int off = 4; off < 64; off <<= 1) {
        sum.x += __shfl_xor(sum.x, off);
        sum.y += __shfl_xor(sum.y, off);
        sum.z += __shfl_xor(sum.z, off);
        sum.w += __shfl_xor(sum.w, off);
    }
    if (slot == 0) {
        float di = dinv[wid];
        sum.x *= di; sum.y *= di; sum.z *= di; sum.w *= di;
        *(float4*)&agg[(size_t)wid * 16 + q * 4] = sum;
    }
}

// MLP head: feat=[x(9),relu(agg3+b3)(16)]; z=relu(feat@Wl2+bl2);
// z2=relu(z@Wl3+bl3); out=z2@Wl4+bl4. 4 waves/block, 16-node tile per wave,
// weights from global (L1/L2); k-loop split in 32KB halves for L1 residency.
// Plain launch_bounds(256): min-waves arg forces 64-VGPR cap + spills.
__global__ __launch_bounds__(256) void k_mlp(const float* __restrict__ x,
                                             const float* __restrict__ agg3,
                                             const float* __restrict__ b3,
                                             const float* __restrict__ Wl2,
                                             const float* __restrict__ bl2,
                                             const float* __restrict__ Wl3,
                                             const float* __restrict__ bl3,
                                             const float* __restrict__ Wl4,
                                             const float* __restrict__ bl4,
                                             float* __restrict__ out, int n)
{
    __shared__ __align__(16) float zs[4][16][132];
    __shared__ __align__(16) float sfeat[4][16][28];

    int tid  = threadIdx.x;
    int w    = tid >> 6;
    int lane = tid & 63;
    int og   = lane & 15;
    int ng   = lane >> 4;
    int base = (blockIdx.x * 4 + w) * 16;

    for (int idx = lane; idx < 16 * 25; idx += 64) {
        int nn = idx / 25, f = idx - nn * 25;
        int node = base + nn;
        float v = 0.f;
        if (node < n) {
            if (f < 9) v = x[(size_t)node * 9 + f];
            else {
                float t = agg3[(size_t)node * 16 + (f - 9)] + b3[f - 9];
                v = t > 0.f ? t : 0.f;
            }
        }
        sfeat[w][nn][f] = v;
    }
    __syncthreads();

    float acc[4][8];
    {
        float4 b0 = *(const float4*)&bl2[og * 8];
        float4 b1 = *(const float4*)&bl2[og * 8 + 4];
#pragma unroll
        for (int i = 0; i < 4; ++i) {
            acc[i][0] = b0.x; acc[i][1] = b0.y; acc[i][2] = b0.z; acc[i][3] = b0.w;
            acc[i][4] = b1.x; acc[i][5] = b1.y; acc[i][6] = b1.z; acc[i][7] = b1.w;
        }
    }
#pragma unroll
    for (int k = 0; k < 25; ++k) {
        float4 w0 = *(const float4*)&Wl2[k * 128 + og * 8];
        float4 w1 = *(const float4*)&Wl2[k * 128 + og * 8 + 4];
#pragma unroll
        for (int i = 0; i < 4; ++i) {
            float f = sfeat[w][ng * 4 + i][k];
            acc[i][0] = fmaf(f, w0.x, acc[i][0]); acc[i][1] = fmaf(f, w0.y, acc[i][1]);
            acc[i][2] = fmaf(f, w0.z, acc[i][2]); acc[i][3] = fmaf(f, w0.w, acc[i][3]);
            acc[i][4] = fmaf(f, w1.x, acc[i][4]); acc[i][5] = fmaf(f, w1.y, acc[i][5]);
            acc[i][6] = fmaf(f, w1.z, acc[i][6]); acc[i][7] = fmaf(f, w1.w, acc[i][7]);
        }
    }
#pragma unroll
    for (int i = 0; i < 4; ++i) {
        float4 lo, hi;
        lo.x = acc[i][0] > 0.f ? acc[i][0] : 0.f; lo.y = acc[i][1] > 0.f ? acc[i][1] : 0.f;
        lo.z = acc[i][2] > 0.f ? acc[i][2] : 0.f; lo.w = acc[i][3] > 0.f ? acc[i][3] : 0.f;
        hi.x = acc[i][4] > 0.f ? acc[i][4] : 0.f; hi.y = acc[i][5] > 0.f ? acc[i][5] : 0.f;
        hi.z = acc[i][6] > 0.f ? acc[i][6] : 0.f; hi.w = acc[i][7] > 0.f ? acc[i][7] : 0.f;
        *(float4*)&zs[w][ng * 4 + i][og * 8]     = lo;
        *(float4*)&zs[w][ng * 4 + i][og * 8 + 4] = hi;
    }
    __syncthreads();

    {
        float4 b0 = *(const float4*)&bl3[og * 8];
        float4 b1 = *(const float4*)&bl3[og * 8 + 4];
#pragma unroll
        for (int i = 0; i < 4; ++i) {
            acc[i][0] = b0.x; acc[i][1] = b0.y; acc[i][2] = b0.z; acc[i][3] = b0.w;
            acc[i][4] = b1.x; acc[i][5] = b1.y; acc[i][6] = b1.z; acc[i][7] = b1.w;
        }
    }
#pragma unroll 2
    for (int k = 0; k < 64; ++k) {
        float4 w0 = *(const float4*)&Wl3[k * 128 + og * 8];
        float4 w1 = *(const float4*)&Wl3[k * 128 + og * 8 + 4];
#pragma unroll
        for (int i = 0; i < 4; ++i) {
            float z = zs[w][ng * 4 + i][k];
            acc[i][0] = fmaf(z, w0.x, acc[i][0]); acc[i][1] = fmaf(z, w0.y, acc[i][1]);
            acc[i][2] = fmaf(z, w0.z, acc[i][2]); acc[i][3] = fmaf(z, w0.w, acc[i][3]);
            acc[i][4] = fmaf(z, w1.x, acc[i][4]); acc[i][5] = fmaf(z, w1.y, acc[i][5]);
            acc[i][6] = fmaf(z, w1.z, acc[i][6]); acc[i][7] = fmaf(z, w1.w, acc[i][7]);
        }
    }
    __syncthreads();    // keep all waves on the same 32KB half of Wl3 (L1)
#pragma unroll 2
    for (int k = 64; k < 128; ++k) {
        float4 w0 = *(const float4*)&Wl3[k * 128 + og * 8];
        float4 w1 = *(const float4*)&Wl3[k * 128 + og * 8 + 4];
#pragma unroll
        for (int i = 0; i < 4; ++i) {
            float z = zs[w][ng * 4 + i][k];
            acc[i][0] = fmaf(z, w0.x, acc[i][0]); acc[i][1] = fmaf(z, w0.y, acc[i][1]);
            acc[i][2] = fmaf(z, w0.z, acc[i][2]); acc[i][3] = fmaf(z, w0.w, acc[i][3]);
            acc[i][4] = fmaf(z, w1.x, acc[i][4]); acc[i][5] = fmaf(z, w1.y, acc[i][5]);
            acc[i][6] = fmaf(z, w1.z, acc[i][6]); acc[i][7] = fmaf(z, w1.w, acc[i][7]);
        }
    }

    {
        float4 w40 = *(const float4*)&Wl4[og * 8];
        float4 w41 = *(const float4*)&Wl4[og * 8 + 4];
        float bb = bl4[0];
#pragma unroll
        for (int i = 0; i < 4; ++i) {
            float p = 0.f;
            p = fmaf(acc[i][0] > 0.f ? acc[i][0] : 0.f, w40.x, p);
            p = fmaf(acc[i][1] > 0.f ? acc[i][1] : 0.f, w40.y, p);
            p = fmaf(acc[i][2] > 0.f ? acc[i][2] : 0.f, w40.z, p);
            p = fmaf(acc[i][3] > 0.f ? acc[i][3] : 0.f, w40.w, p);
            p = fmaf(acc[i][4] > 0.f ? acc[i][4] : 0.f, w41.x, p);
            p = fmaf(acc[i][5] > 0.f ? acc[i][5] : 0.f, w41.y, p);
            p = fmaf(acc[i][6] > 0.f ? acc[i][6] : 0.f, w41.z, p);
            p = fmaf(acc[i][7] > 0.f ? acc[i][7] : 0.f, w41.w, p);
            p += __shfl_xor(p, 1);
            p += __shfl_xor(p, 2);
            p += __shfl_xor(p, 4);
            p += __shfl_xor(p, 8);
            int node = base + ng * 4 + i;
            if (og == 0 && node < n) out[node] = p + bb;
        }
    }
}

extern "C" void kernel_launch(void* const* d_in, const int* in_sizes, int n_in,
                              void* d_out, int out_size, void* d_ws, size_t ws_size,
                              hipStream_t stream)
{
    const float* x   = (const float*)d_in[0];
    const void*  ei  = d_in[1];
    const float* W1  = (const float*)d_in[2];
    const float* b1  = (const float*)d_in[3];
    const float* W2  = (const float*)d_in[4];
    const float* b2  = (const float*)d_in[5];
    const float* W3  = (const float*)d_in[6];
    const float* b3  = (const float*)d_in[7];
    const float* Wl2 = (const float*)d_in[8];
    const float* bl2 = (const float*)d_in[9];
    const float* Wl3 = (const float*)d_in[10];
    const float* bl3 = (const float*)d_in[11];
    const float* Wl4 = (const float*)d_in[12];
    const float* bl4 = (const float*)d_in[13];
    float* out = (float*)d_out;

    int n        = in_sizes[0] / 9;          // 250000
    long long e2 = (long long)in_sizes[1];   // 2*E
    long long E  = e2 / 2;
    int NB       = (n + BSZ - 1) >> BSH;     // 489 buckets
    int L        = NB * NBLK + 1;            // scan length (extra slot = total)
    size_t EPAD  = (size_t)E + (size_t)NBLK * NB * 16;   // binned region elems

    char* ws = (char*)d_ws;
    size_t off = 0;
    int*   flag     = (int*)(ws + off); off += 256;
    int*   cnt_blk  = (int*)(ws + off); off += (size_t)L * 4;        off = (off + 255) & ~(size_t)255;
    int*   base_blk = (int*)(ws + off); off += (size_t)L * 4;        off = (off + 255) & ~(size_t)255;
    int*   partials = (int*)(ws + off); off += 16384;
    float* dinv     = (float*)(ws + off); off += (size_t)n * 4;      off = (off + 255) & ~(size_t)255;
    int*   degi     = (int*)(ws + off); off += (size_t)n * 4;        off = (off + 255) & ~(size_t)255;
    int*   row_off  = (int*)(ws + off); off += (size_t)n * 4;        off = (off + 255) & ~(size_t)255;
    int*   csr      = (int*)(ws + off); off += EPAD * 4;             off = (off + 255) & ~(size_t)255;
    int*   epk      = (int*)(ws + off); off += EPAD * 4;             off = (off + 255) & ~(size_t)255;
    // hs/agg alias epk (dead after k_csr); EPAD*4 = 36 MB >= 32 MB needed
    float* hs  = (float*)epk;
    float* agg = hs + (size_t)n * 16;

    int nb_n = (n + 255) / 256;
    int nb_s = (L + 255) / 256;

    k_detect<<<1, 64, 0, stream>>>(ei, flag, n);
    hipMemsetAsync(cnt_blk + (L - 1), 0, 4, stream);   // extra slot -> total
    k_hist2<<<NBLK, 256, 0, stream>>>(ei, flag, cnt_blk, E, NB);
    k_scan1<<<nb_s, 256, 0, stream>>>(cnt_blk, base_blk, partials, L);
    k_scan2<<<1, 1024, 0, stream>>>(partials, nb_s);
    k_scan3<<<nb_s, 256, 0, stream>>>(base_blk, partials, L);
    k_bin<<<NBLK, 256, 0, stream>>>(ei, flag, base_blk, epk, E, NB);
    k_csr<<<NB, 256, 0, stream>>>(epk, base_blk, csr, row_off, degi, dinv, n);

    int nb_g = (n + 3) / 4;   // one wave per node, 4 waves/block
    // layer 1
    k_lin1<<<nb_n, 256, 0, stream>>>(x, W1, dinv, hs, n);
    k_gather<<<nb_g, 256, 0, stream>>>(csr, row_off, degi, dinv, hs, agg, n);
    // layer 2
    k_lin_mid<<<nb_n, 256, 0, stream>>>(b1, W2, dinv, agg, hs, n);
    k_gather<<<nb_g, 256, 0, stream>>>(csr, row_off, degi, dinv, hs, agg, n);
    // layer 3
    k_lin_mid<<<nb_n, 256, 0, stream>>>(b2, W3, dinv, agg, hs, n);
    k_gather<<<nb_g, 256, 0, stream>>>(csr, row_off, degi, dinv, hs, agg, n);
    // MLP head
    k_mlp<<<(n + 63) / 64, 256, 0, stream>>>(x, agg, b3, Wl2, bl2, Wl3, bl3, Wl4, bl4,
                                             out, n);
}

// Round 8
// 602.703 us; speedup vs baseline: 3.8911x; 1.0212x over previous
//
#include <hip/hip_runtime.h>

// ---------------------------------------------------------------------------
// GCN: 3x GCNConv(9->16->16->16) + MLP(concat 25 ->128->128->1), N=250000,
// E=5,000,000 edges + self loops. f32 in/out; edge_index int32 OR int64
// (detected on device).
// Pipeline: deterministic 2-pass binning into 512-node buckets (single-writer
// 64B lines, zero global atomics) -> within-bucket counting sort to exact CSR
// (fused deg/dinv) -> per-node wave gather (16 slots x float4, high MLP) ->
// register-blocked MLP head (k4-blocked float4 LDS reads).
// NOTE: k_mlp uses plain __launch_bounds__(256): any min-waves second arg
// makes the allocator cap at 64 VGPRs and spill the acc tile to scratch
// (observed r2/r5/r6: 190MB scratch traffic, 2-3x slowdown).
// ---------------------------------------------------------------------------

#define NBLK 512          // binning blocks (each owns a contiguous edge chunk)
#define BSH  9            // bucket shift: 512 nodes per bucket
#define BSZ  512
#define MAXNB 1024        // max buckets supported (n <= 524288)

__global__ __launch_bounds__(64) void k_detect(const void* __restrict__ edges,
                                               int* __restrict__ flag, int n_nodes)
{
    if (threadIdx.x == 0 && blockIdx.x == 0) {
        const long long* p = (const long long*)edges;
        int is64 = 1;
        for (int i = 0; i < 16; ++i) {
            long long v = p[i];
            if (v < 0 || v >= (long long)n_nodes) is64 = 0;
        }
        *flag = is64;
    }
}

// little-endian: low 32 bits of int64 value < 2^31 equal the int32 value
__device__ __forceinline__ int ld_idx(const void* edges, int f64, long long idx)
{
    return f64 ? ((const int*)edges)[idx << 1] : ((const int*)edges)[idx];
}

// per-block bucket histogram of dst; write rounded-to-16 counts bucket-major
__global__ __launch_bounds__(256) void k_hist2(const void* __restrict__ edges,
                                               const int* __restrict__ flag,
                                               int* __restrict__ cnt_blk,
                                               long long E, int NB)
{
    __shared__ int cnt[MAXNB];
    int tid = threadIdx.x;
    for (int b = tid; b < NB; b += 256) cnt[b] = 0;
    __syncthreads();
    int f64 = *flag;
    long long chunk = (E + NBLK - 1) / NBLK;
    long long lo = (long long)blockIdx.x * chunk;
    long long hi = lo + chunk; if (hi > E) hi = E;
    for (long long i = lo + tid; i < hi; i += 256) {
        int d = ld_idx(edges, f64, E + i);
        atomicAdd(&cnt[d >> BSH], 1);
    }
    __syncthreads();
    for (int b = tid; b < NB; b += 256)
        cnt_blk[(size_t)b * NBLK + blockIdx.x] = (cnt[b] + 15) & ~15;
}

// exclusive scan stage 1
__global__ __launch_bounds__(256) void k_scan1(const int* __restrict__ in,
                                               int* __restrict__ excl,
                                               int* __restrict__ partials, int n)
{
    __shared__ int s[256];
    int tid = threadIdx.x;
    int i = blockIdx.x * 256 + tid;
    int v = (i < n) ? in[i] : 0;
    s[tid] = v;
    __syncthreads();
#pragma unroll
    for (int off = 1; off < 256; off <<= 1) {
        int t = (tid >= off) ? s[tid - off] : 0;
        __syncthreads();
        s[tid] += t;
        __syncthreads();
    }
    if (i < n) excl[i] = s[tid] - v;
    if (tid == 255) partials[blockIdx.x] = s[255];
}

// stage 2: single block, exclusive scan of partials (carry loop)
__global__ __launch_bounds__(1024) void k_scan2(int* __restrict__ p, int nb)
{
    __shared__ int s[1024];
    __shared__ int carry_s;
    int t = threadIdx.x;
    if (t == 0) carry_s = 0;
    __syncthreads();
    for (int base = 0; base < nb; base += 1024) {
        int idx = base + t;
        int v = (idx < nb) ? p[idx] : 0;
        s[t] = v;
        __syncthreads();
        for (int off = 1; off < 1024; off <<= 1) {
            int u = (t >= off) ? s[t - off] : 0;
            __syncthreads();
            s[t] += u;
            __syncthreads();
        }
        int carry = carry_s;
        if (idx < nb) p[idx] = carry + s[t] - v;
        __syncthreads();
        if (t == 0) carry_s += s[1023];
        __syncthreads();
    }
}

// stage 3: add block offsets
__global__ __launch_bounds__(256) void k_scan3(int* __restrict__ excl,
                                               const int* __restrict__ partials, int n)
{
    int i = blockIdx.x * 256 + threadIdx.x;
    if (i < n) excl[i] += partials[blockIdx.x];
}

// re-histogram own chunk, scatter packed edges into own 64B-aligned regions;
// sentinel-fill pad. Zero global atomics.
__global__ __launch_bounds__(256) void k_bin(const void* __restrict__ edges,
                                             const int* __restrict__ flag,
                                             const int* __restrict__ base_blk,
                                             int* __restrict__ epk,
                                             long long E, int NB)
{
    __shared__ int cnt[MAXNB];
    __shared__ int base[MAXNB];
    __shared__ int cur[MAXNB];
    int tid = threadIdx.x;
    for (int b = tid; b < NB; b += 256) cnt[b] = 0;
    __syncthreads();
    int f64 = *flag;
    long long chunk = (E + NBLK - 1) / NBLK;
    long long lo = (long long)blockIdx.x * chunk;
    long long hi = lo + chunk; if (hi > E) hi = E;
    for (long long i = lo + tid; i < hi; i += 256) {
        int d = ld_idx(edges, f64, E + i);
        atomicAdd(&cnt[d >> BSH], 1);
    }
    __syncthreads();
    for (int b = tid; b < NB; b += 256) {
        base[b] = base_blk[(size_t)b * NBLK + blockIdx.x];
        cur[b] = 0;
    }
    __syncthreads();
    for (long long i = lo + tid; i < hi; i += 256) {
        int s = ld_idx(edges, f64, i);
        int d = ld_idx(edges, f64, E + i);
        int b = d >> BSH;
        int slot = atomicAdd(&cur[b], 1);
        epk[base[b] + slot] = ((d & (BSZ - 1)) << 18) | s;
    }
    __syncthreads();
    for (int b = tid; b < NB; b += 256) {
        int c = cnt[b];
        int r = (c + 15) & ~15;
        for (int j = c; j < r; ++j) epk[base[b] + j] = -1;
    }
}

// within-bucket counting sort -> exact CSR; fused deg/dinv/row_off.
__global__ __launch_bounds__(256) void k_csr(const int* __restrict__ epk,
                                             const int* __restrict__ base_blk,
                                             int* __restrict__ csr,
                                             int* __restrict__ row_off,
                                             int* __restrict__ degi,
                                             float* __restrict__ dinv, int n)
{
    __shared__ int cnt[BSZ];
    __shared__ int off[BSZ];
    __shared__ int ps[256];
    int b = blockIdx.x;
    int tid = threadIdx.x;
    int start = base_blk[(size_t)b * NBLK];
    int end   = base_blk[(size_t)(b + 1) * NBLK];
    cnt[tid] = 0; cnt[tid + 256] = 0;
    __syncthreads();
    for (int e = start + tid; e < end; e += 256) {
        int pk = epk[e];
        if (pk >= 0) atomicAdd(&cnt[pk >> 18], 1);
    }
    __syncthreads();
    int pairSum = cnt[2 * tid] + cnt[2 * tid + 1];
    ps[tid] = pairSum;
    __syncthreads();
#pragma unroll
    for (int o = 1; o < 256; o <<= 1) {
        int v = (tid >= o) ? ps[tid - o] : 0;
        __syncthreads();
        ps[tid] += v;
        __syncthreads();
    }
    int incl = ps[tid];
    off[2 * tid]     = incl - pairSum;
    off[2 * tid + 1] = incl - pairSum + cnt[2 * tid];
    __syncthreads();
    int nbase = b << BSH;
#pragma unroll
    for (int l = tid; l < BSZ; l += 256) {
        int node = nbase + l;
        if (node < n) {
            row_off[node] = start + off[l];
            degi[node]    = cnt[l];
            dinv[node]    = rsqrtf((float)cnt[l] + 1.0f);
        }
    }
    __syncthreads();
    for (int e = start + tid; e < end; e += 256) {
        int pk = epk[e];
        if (pk < 0) continue;
        int l = pk >> 18;
        int pos = atomicAdd(&off[l], 1);
        csr[start + pos] = pk & 0x3FFFF;
    }
}

// h = x @ W1 (9->16); hs = h * dinv
__global__ __launch_bounds__(256) void k_lin1(const float* __restrict__ x,
                                              const float* __restrict__ W1,
                                              const float* __restrict__ dinv,
                                              float* __restrict__ hs, int n)
{
    __shared__ float sW[144];
    if (threadIdx.x < 144) sW[threadIdx.x] = W1[threadIdx.x];
    __syncthreads();
    int i = blockIdx.x * 256 + threadIdx.x;
    if (i >= n) return;
    float xv[9];
#pragma unroll
    for (int k = 0; k < 9; ++k) xv[k] = x[(size_t)i * 9 + k];
    float di = dinv[i];
#pragma unroll
    for (int j = 0; j < 16; ++j) {
        float acc = 0.f;
#pragma unroll
        for (int k = 0; k < 9; ++k) acc = fmaf(xv[k], sW[k * 16 + j], acc);
        hs[(size_t)i * 16 + j] = acc * di;
    }
}

// t = relu(agg + bias); h = t @ W (16->16); hs = h * dinv
__global__ __launch_bounds__(256) void k_lin_mid(const float* __restrict__ bias,
                                                 const float* __restrict__ W,
                                                 const float* __restrict__ dinv,
                                                 const float* __restrict__ agg,
                                                 float* __restrict__ hs, int n)
{
    __shared__ float sW[256];
    __shared__ float sB[16];
    sW[threadIdx.x] = W[threadIdx.x];
    if (threadIdx.x < 16) sB[threadIdx.x] = bias[threadIdx.x];
    __syncthreads();
    int i = blockIdx.x * 256 + threadIdx.x;
    if (i >= n) return;
    float t[16];
#pragma unroll
    for (int k = 0; k < 16; ++k) {
        float v = agg[(size_t)i * 16 + k] + sB[k];
        t[k] = v > 0.f ? v : 0.f;
    }
    float di = dinv[i];
#pragma unroll
    for (int j = 0; j < 16; ++j) {
        float acc = 0.f;
#pragma unroll
        for (int k = 0; k < 16; ++k) acc = fmaf(t[k], sW[k * 16 + j], acc);
        hs[(size_t)i * 16 + j] = acc * di;
    }
}

// One wave per node, 16 edge-slots x 4 lanes (float4 each): 16 independent
// random 64B lines in flight per wave. agg[d]=dinv[d]*(hs[d]+sum hs[src]).
__global__ __launch_bounds__(256) void k_gather(const int* __restrict__ csr,
                                                const int* __restrict__ row_off,
                                                const int* __restrict__ degi,
                                                const float* __restrict__ dinv,
                                                const float* __restrict__ hs,
                                                float* __restrict__ agg, int n)
{
    int wid = (int)(((long long)blockIdx.x * 256 + threadIdx.x) >> 6);
    if (wid >= n) return;
    int lane = threadIdx.x & 63;
    int slot = lane >> 2;          // 16 slots
    int q    = lane & 3;           // float4 quarter of the 16-feature row
    int start = row_off[wid];
    int deg   = degi[wid];
    float4 sum;
    if (slot == 0) sum = *(const float4*)&hs[(size_t)wid * 16 + q * 4]; // self loop
    else           sum = make_float4(0.f, 0.f, 0.f, 0.f);
    for (int e = slot; e < deg; e += 16) {
        int s = csr[start + e];
        float4 v = *(const float4*)&hs[(size_t)s * 16 + q * 4];
        sum.x += v.x; sum.y += v.y; sum.z += v.z; sum.w += v.w;
    }
#pragma unroll
    for (int off = 4; off < 64; off <<= 1) {
        sum.x += __shfl_xor(sum.x, off);
        sum.y += __shfl_xor(sum.y, off);
        sum.z += __shfl_xor(sum.z, off);
        sum.w += __shfl_xor(sum.w, off);
    }
    if (slot == 0) {
        float di = dinv[wid];
        sum.x *= di; sum.y *= di; sum.z *= di; sum.w *= di;
        *(float4*)&agg[(size_t)wid * 16 + q * 4] = sum;
    }
}

// MLP head: feat=[x(9),relu(agg3+b3)(16)]; z=relu(feat@Wl2+bl2);
// z2=relu(z@Wl3+bl3); out=z2@Wl4+bl4. 4 waves/block, 16-node tile per wave,
// weights from global (L1/L2); l3 k-loop blocked by 4 with float4 LDS z
// reads ([132] pad -> ng rows land on disjoint banks); k halves split by a
// barrier for Wl3 L1 residency.
// Plain launch_bounds(256): min-waves arg forces 64-VGPR cap + spills.
__global__ __launch_bounds__(256) void k_mlp(const float* __restrict__ x,
                                             const float* __restrict__ agg3,
                                             const float* __restrict__ b3,
                                             const float* __restrict__ Wl2,
                                             const float* __restrict__ bl2,
                                             const float* __restrict__ Wl3,
                                             const float* __restrict__ bl3,
                                             const float* __restrict__ Wl4,
                                             const float* __restrict__ bl4,
                                             float* __restrict__ out, int n)
{
    __shared__ __align__(16) float zs[4][16][132];
    __shared__ __align__(16) float sfeat[4][16][28];

    int tid  = threadIdx.x;
    int w    = tid >> 6;
    int lane = tid & 63;
    int og   = lane & 15;
    int ng   = lane >> 4;
    int base = (blockIdx.x * 4 + w) * 16;

    for (int idx = lane; idx < 16 * 25; idx += 64) {
        int nn = idx / 25, f = idx - nn * 25;
        int node = base + nn;
        float v = 0.f;
        if (node < n) {
            if (f < 9) v = x[(size_t)node * 9 + f];
            else {
                float t = agg3[(size_t)node * 16 + (f - 9)] + b3[f - 9];
                v = t > 0.f ? t : 0.f;
            }
        }
        sfeat[w][nn][f] = v;
    }
    __syncthreads();

    float acc[4][8];
    // ---- layer l2: feat[16][25] @ Wl2[25][128] -> zs ----
    {
        float4 b0 = *(const float4*)&bl2[og * 8];
        float4 b1 = *(const float4*)&bl2[og * 8 + 4];
#pragma unroll
        for (int i = 0; i < 4; ++i) {
            acc[i][0] = b0.x; acc[i][1] = b0.y; acc[i][2] = b0.z; acc[i][3] = b0.w;
            acc[i][4] = b1.x; acc[i][5] = b1.y; acc[i][6] = b1.z; acc[i][7] = b1.w;
        }
    }
#pragma unroll
    for (int k = 0; k < 25; ++k) {
        float4 w0 = *(const float4*)&Wl2[k * 128 + og * 8];
        float4 w1 = *(const float4*)&Wl2[k * 128 + og * 8 + 4];
#pragma unroll
        for (int i = 0; i < 4; ++i) {
            float f = sfeat[w][ng * 4 + i][k];
            acc[i][0] = fmaf(f, w0.x, acc[i][0]); acc[i][1] = fmaf(f, w0.y, acc[i][1]);
            acc[i][2] = fmaf(f, w0.z, acc[i][2]); acc[i][3] = fmaf(f, w0.w, acc[i][3]);
            acc[i][4] = fmaf(f, w1.x, acc[i][4]); acc[i][5] = fmaf(f, w1.y, acc[i][5]);
            acc[i][6] = fmaf(f, w1.z, acc[i][6]); acc[i][7] = fmaf(f, w1.w, acc[i][7]);
        }
    }
#pragma unroll
    for (int i = 0; i < 4; ++i) {
        float4 lo, hi;
        lo.x = acc[i][0] > 0.f ? acc[i][0] : 0.f; lo.y = acc[i][1] > 0.f ? acc[i][1] : 0.f;
        lo.z = acc[i][2] > 0.f ? acc[i][2] : 0.f; lo.w = acc[i][3] > 0.f ? acc[i][3] : 0.f;
        hi.x = acc[i][4] > 0.f ? acc[i][4] : 0.f; hi.y = acc[i][5] > 0.f ? acc[i][5] : 0.f;
        hi.z = acc[i][6] > 0.f ? acc[i][6] : 0.f; hi.w = acc[i][7] > 0.f ? acc[i][7] : 0.f;
        *(float4*)&zs[w][ng * 4 + i][og * 8]     = lo;
        *(float4*)&zs[w][ng * 4 + i][og * 8 + 4] = hi;
    }
    __syncthreads();

    // ---- layer l3: z[16][128] @ Wl3[128][128], k-blocked by 4 ----
    {
        float4 b0 = *(const float4*)&bl3[og * 8];
        float4 b1 = *(const float4*)&bl3[og * 8 + 4];
#pragma unroll
        for (int i = 0; i < 4; ++i) {
            acc[i][0] = b0.x; acc[i][1] = b0.y; acc[i][2] = b0.z; acc[i][3] = b0.w;
            acc[i][4] = b1.x; acc[i][5] = b1.y; acc[i][6] = b1.z; acc[i][7] = b1.w;
        }
    }
#pragma unroll 2
    for (int k4 = 0; k4 < 64; k4 += 4) {
        float4 z4[4];
#pragma unroll
        for (int i = 0; i < 4; ++i)
            z4[i] = *(const float4*)&zs[w][ng * 4 + i][k4];
#pragma unroll
        for (int kk = 0; kk < 4; ++kk) {
            const float* wr = &Wl3[(k4 + kk) * 128 + og * 8];
            float4 w0 = *(const float4*)wr;
            float4 w1 = *(const float4*)(wr + 4);
#pragma unroll
            for (int i = 0; i < 4; ++i) {
                float zz = (kk == 0) ? z4[i].x : (kk == 1) ? z4[i].y
                         : (kk == 2) ? z4[i].z : z4[i].w;
                acc[i][0] = fmaf(zz, w0.x, acc[i][0]); acc[i][1] = fmaf(zz, w0.y, acc[i][1]);
                acc[i][2] = fmaf(zz, w0.z, acc[i][2]); acc[i][3] = fmaf(zz, w0.w, acc[i][3]);
                acc[i][4] = fmaf(zz, w1.x, acc[i][4]); acc[i][5] = fmaf(zz, w1.y, acc[i][5]);
                acc[i][6] = fmaf(zz, w1.z, acc[i][6]); acc[i][7] = fmaf(zz, w1.w, acc[i][7]);
            }
        }
    }
    __syncthreads();    // keep all waves on the same 32KB half of Wl3 (L1)
#pragma unroll 2
    for (int k4 = 64; k4 < 128; k4 += 4) {
        float4 z4[4];
#pragma unroll
        for (int i = 0; i < 4; ++i)
            z4[i] = *(const float4*)&zs[w][ng * 4 + i][k4];
#pragma unroll
        for (int kk = 0; kk < 4; ++kk) {
            const float* wr = &Wl3[(k4 + kk) * 128 + og * 8];
            float4 w0 = *(const float4*)wr;
            float4 w1 = *(const float4*)(wr + 4);
#pragma unroll
            for (int i = 0; i < 4; ++i) {
                float zz = (kk == 0) ? z4[i].x : (kk == 1) ? z4[i].y
                         : (kk == 2) ? z4[i].z : z4[i].w;
                acc[i][0] = fmaf(zz, w0.x, acc[i][0]); acc[i][1] = fmaf(zz, w0.y, acc[i][1]);
                acc[i][2] = fmaf(zz, w0.z, acc[i][2]); acc[i][3] = fmaf(zz, w0.w, acc[i][3]);
                acc[i][4] = fmaf(zz, w1.x, acc[i][4]); acc[i][5] = fmaf(zz, w1.y, acc[i][5]);
                acc[i][6] = fmaf(zz, w1.z, acc[i][6]); acc[i][7] = fmaf(zz, w1.w, acc[i][7]);
            }
        }
    }

    // ---- layer l4: relu, dot with Wl4, reduce over og ----
    {
        float4 w40 = *(const float4*)&Wl4[og * 8];
        float4 w41 = *(const float4*)&Wl4[og * 8 + 4];
        float bb = bl4[0];
#pragma unroll
        for (int i = 0; i < 4; ++i) {
            float p = 0.f;
            p = fmaf(acc[i][0] > 0.f ? acc[i][0] : 0.f, w40.x, p);
            p = fmaf(acc[i][1] > 0.f ? acc[i][1] : 0.f, w40.y, p);
            p = fmaf(acc[i][2] > 0.f ? acc[i][2] : 0.f, w40.z, p);
            p = fmaf(acc[i][3] > 0.f ? acc[i][3] : 0.f, w40.w, p);
            p = fmaf(acc[i][4] > 0.f ? acc[i][4] : 0.f, w41.x, p);
            p = fmaf(acc[i][5] > 0.f ? acc[i][5] : 0.f, w41.y, p);
            p = fmaf(acc[i][6] > 0.f ? acc[i][6] : 0.f, w41.z, p);
            p = fmaf(acc[i][7] > 0.f ? acc[i][7] : 0.f, w41.w, p);
            p += __shfl_xor(p, 1);
            p += __shfl_xor(p, 2);
            p += __shfl_xor(p, 4);
            p += __shfl_xor(p, 8);
            int node = base + ng * 4 + i;
            if (og == 0 && node < n) out[node] = p + bb;
        }
    }
}

extern "C" void kernel_launch(void* const* d_in, const int* in_sizes, int n_in,
                              void* d_out, int out_size, void* d_ws, size_t ws_size,
                              hipStream_t stream)
{
    const float* x   = (const float*)d_in[0];
    const void*  ei  = d_in[1];
    const float* W1  = (const float*)d_in[2];
    const float* b1  = (const float*)d_in[3];
    const float* W2  = (const float*)d_in[4];
    const float* b2  = (const float*)d_in[5];
    const float* W3  = (const float*)d_in[6];
    const float* b3  = (const float*)d_in[7];
    const float* Wl2 = (const float*)d_in[8];
    const float* bl2 = (const float*)d_in[9];
    const float* Wl3 = (const float*)d_in[10];
    const float* bl3 = (const float*)d_in[11];
    const float* Wl4 = (const float*)d_in[12];
    const float* bl4 = (const float*)d_in[13];
    float* out = (float*)d_out;

    int n        = in_sizes[0] / 9;          // 250000
    long long e2 = (long long)in_sizes[1];   // 2*E
    long long E  = e2 / 2;
    int NB       = (n + BSZ - 1) >> BSH;     // 489 buckets
    int L        = NB * NBLK + 1;            // scan length (extra slot = total)
    size_t EPAD  = (size_t)E + (size_t)NBLK * NB * 16;   // binned region elems

    char* ws = (char*)d_ws;
    size_t off = 0;
    int*   flag     = (int*)(ws + off); off += 256;
    int*   cnt_blk  = (int*)(ws + off); off += (size_t)L * 4;        off = (off + 255) & ~(size_t)255;
    int*   base_blk = (int*)(ws + off); off += (size_t)L * 4;        off = (off + 255) & ~(size_t)255;
    int*   partials = (int*)(ws + off); off += 16384;
    float* dinv     = (float*)(ws + off); off += (size_t)n * 4;      off = (off + 255) & ~(size_t)255;
    int*   degi     = (int*)(ws + off); off += (size_t)n * 4;        off = (off + 255) & ~(size_t)255;
    int*   row_off  = (int*)(ws + off); off += (size_t)n * 4;        off = (off + 255) & ~(size_t)255;
    int*   csr      = (int*)(ws + off); off += EPAD * 4;             off = (off + 255) & ~(size_t)255;
    int*   epk      = (int*)(ws + off); off += EPAD * 4;             off = (off + 255) & ~(size_t)255;
    // hs/agg alias epk (dead after k_csr); EPAD*4 = 36 MB >= 32 MB needed
    float* hs  = (float*)epk;
    float* agg = hs + (size_t)n * 16;

    int nb_n = (n + 255) / 256;
    int nb_s = (L + 255) / 256;

    k_detect<<<1, 64, 0, stream>>>(ei, flag, n);
    hipMemsetAsync(cnt_blk + (L - 1), 0, 4, stream);   // extra slot -> total
    k_hist2<<<NBLK, 256, 0, stream>>>(ei, flag, cnt_blk, E, NB);
    k_scan1<<<nb_s, 256, 0, stream>>>(cnt_blk, base_blk, partials, L);
    k_scan2<<<1, 1024, 0, stream>>>(partials, nb_s);
    k_scan3<<<nb_s, 256, 0, stream>>>(base_blk, partials, L);
    k_bin<<<NBLK, 256, 0, stream>>>(ei, flag, base_blk, epk, E, NB);
    k_csr<<<NB, 256, 0, stream>>>(epk, base_blk, csr, row_off, degi, dinv, n);

    int nb_g = (n + 3) / 4;   // one wave per node, 4 waves/block
    // layer 1
    k_lin1<<<nb_n, 256, 0, stream>>>(x, W1, dinv, hs, n);
    k_gather<<<nb_g, 256, 0, stream>>>(csr, row_off, degi, dinv, hs, agg, n);
    // layer 2
    k_lin_mid<<<nb_n, 256, 0, stream>>>(b1, W2, dinv, agg, hs, n);
    k_gather<<<nb_g, 256, 0, stream>>>(csr, row_off, degi, dinv, hs, agg, n);
    // layer 3
    k_lin_mid<<<nb_n, 256, 0, stream>>>(b2, W3, dinv, agg, hs, n);
    k_gather<<<nb_g, 256, 0, stream>>>(csr, row_off, degi, dinv, hs, agg, n);
    // MLP head
    k_mlp<<<(n + 63) / 64, 256, 0, stream>>>(x, agg, b3, Wl2, bl2, Wl3, bl3, Wl4, bl4,
                                             out, n);
}

// Round 9
// 593.325 us; speedup vs baseline: 3.9526x; 1.0158x over previous
//
#include <hip/hip_runtime.h>

// ---------------------------------------------------------------------------
// GCN: 3x GCNConv(9->16->16->16) + MLP(concat 25 ->128->128->1), N=250000,
// E=5,000,000 edges + self loops. f32 in/out; edge_index int32 OR int64
// (detected on device).
// Pipeline: deterministic 2-pass binning into 512-node buckets (single-writer
// 64B lines, zero global atomics) -> within-bucket counting sort to exact CSR
// (fused deg/dinv) -> per-node wave gather with FUSED 16x16 linear epilogue
// (shuffle-GEMV) -> register-blocked MLP head (32KB LDS, swizzled zs).
// NOTE: k_mlp uses plain __launch_bounds__(256): any min-waves second arg
// makes the allocator cap at 64 VGPRs and spill the acc tile to scratch
// (observed r2/r5/r6: 190MB scratch traffic, 2-3x slowdown).
// ---------------------------------------------------------------------------

#define NBLK 512          // binning blocks (each owns a contiguous edge chunk)
#define BSH  9            // bucket shift: 512 nodes per bucket
#define BSZ  512
#define MAXNB 1024        // max buckets supported (n <= 524288)

__global__ __launch_bounds__(64) void k_detect(const void* __restrict__ edges,
                                               int* __restrict__ flag, int n_nodes)
{
    if (threadIdx.x == 0 && blockIdx.x == 0) {
        const long long* p = (const long long*)edges;
        int is64 = 1;
        for (int i = 0; i < 16; ++i) {
            long long v = p[i];
            if (v < 0 || v >= (long long)n_nodes) is64 = 0;
        }
        *flag = is64;
    }
}

// little-endian: low 32 bits of int64 value < 2^31 equal the int32 value
__device__ __forceinline__ int ld_idx(const void* edges, int f64, long long idx)
{
    return f64 ? ((const int*)edges)[idx << 1] : ((const int*)edges)[idx];
}

// per-block bucket histogram of dst; write rounded-to-16 counts bucket-major
__global__ __launch_bounds__(256) void k_hist2(const void* __restrict__ edges,
                                               const int* __restrict__ flag,
                                               int* __restrict__ cnt_blk,
                                               long long E, int NB)
{
    __shared__ int cnt[MAXNB];
    int tid = threadIdx.x;
    for (int b = tid; b < NB; b += 256) cnt[b] = 0;
    __syncthreads();
    int f64 = *flag;
    long long chunk = (E + NBLK - 1) / NBLK;
    long long lo = (long long)blockIdx.x * chunk;
    long long hi = lo + chunk; if (hi > E) hi = E;
    for (long long i = lo + tid; i < hi; i += 256) {
        int d = ld_idx(edges, f64, E + i);
        atomicAdd(&cnt[d >> BSH], 1);
    }
    __syncthreads();
    for (int b = tid; b < NB; b += 256)
        cnt_blk[(size_t)b * NBLK + blockIdx.x] = (cnt[b] + 15) & ~15;
}

// exclusive scan stage 1
__global__ __launch_bounds__(256) void k_scan1(const int* __restrict__ in,
                                               int* __restrict__ excl,
                                               int* __restrict__ partials, int n)
{
    __shared__ int s[256];
    int tid = threadIdx.x;
    int i = blockIdx.x * 256 + tid;
    int v = (i < n) ? in[i] : 0;
    s[tid] = v;
    __syncthreads();
#pragma unroll
    for (int off = 1; off < 256; off <<= 1) {
        int t = (tid >= off) ? s[tid - off] : 0;
        __syncthreads();
        s[tid] += t;
        __syncthreads();
    }
    if (i < n) excl[i] = s[tid] - v;
    if (tid == 255) partials[blockIdx.x] = s[255];
}

// stage 2: single block, exclusive scan of partials (carry loop)
__global__ __launch_bounds__(1024) void k_scan2(int* __restrict__ p, int nb)
{
    __shared__ int s[1024];
    __shared__ int carry_s;
    int t = threadIdx.x;
    if (t == 0) carry_s = 0;
    __syncthreads();
    for (int base = 0; base < nb; base += 1024) {
        int idx = base + t;
        int v = (idx < nb) ? p[idx] : 0;
        s[t] = v;
        __syncthreads();
        for (int off = 1; off < 1024; off <<= 1) {
            int u = (t >= off) ? s[t - off] : 0;
            __syncthreads();
            s[t] += u;
            __syncthreads();
        }
        int carry = carry_s;
        if (idx < nb) p[idx] = carry + s[t] - v;
        __syncthreads();
        if (t == 0) carry_s += s[1023];
        __syncthreads();
    }
}

// stage 3: add block offsets
__global__ __launch_bounds__(256) void k_scan3(int* __restrict__ excl,
                                               const int* __restrict__ partials, int n)
{
    int i = blockIdx.x * 256 + threadIdx.x;
    if (i < n) excl[i] += partials[blockIdx.x];
}

// re-histogram own chunk, scatter packed edges into own 64B-aligned regions;
// sentinel-fill pad. Zero global atomics.
__global__ __launch_bounds__(256) void k_bin(const void* __restrict__ edges,
                                             const int* __restrict__ flag,
                                             const int* __restrict__ base_blk,
                                             int* __restrict__ epk,
                                             long long E, int NB)
{
    __shared__ int cnt[MAXNB];
    __shared__ int base[MAXNB];
    __shared__ int cur[MAXNB];
    int tid = threadIdx.x;
    for (int b = tid; b < NB; b += 256) cnt[b] = 0;
    __syncthreads();
    int f64 = *flag;
    long long chunk = (E + NBLK - 1) / NBLK;
    long long lo = (long long)blockIdx.x * chunk;
    long long hi = lo + chunk; if (hi > E) hi = E;
    for (long long i = lo + tid; i < hi; i += 256) {
        int d = ld_idx(edges, f64, E + i);
        atomicAdd(&cnt[d >> BSH], 1);
    }
    __syncthreads();
    for (int b = tid; b < NB; b += 256) {
        base[b] = base_blk[(size_t)b * NBLK + blockIdx.x];
        cur[b] = 0;
    }
    __syncthreads();
    for (long long i = lo + tid; i < hi; i += 256) {
        int s = ld_idx(edges, f64, i);
        int d = ld_idx(edges, f64, E + i);
        int b = d >> BSH;
        int slot = atomicAdd(&cur[b], 1);
        epk[base[b] + slot] = ((d & (BSZ - 1)) << 18) | s;
    }
    __syncthreads();
    for (int b = tid; b < NB; b += 256) {
        int c = cnt[b];
        int r = (c + 15) & ~15;
        for (int j = c; j < r; ++j) epk[base[b] + j] = -1;
    }
}

// within-bucket counting sort -> exact CSR; fused deg/dinv/row_off.
__global__ __launch_bounds__(256) void k_csr(const int* __restrict__ epk,
                                             const int* __restrict__ base_blk,
                                             int* __restrict__ csr,
                                             int* __restrict__ row_off,
                                             int* __restrict__ degi,
                                             float* __restrict__ dinv, int n)
{
    __shared__ int cnt[BSZ];
    __shared__ int off[BSZ];
    __shared__ int ps[256];
    int b = blockIdx.x;
    int tid = threadIdx.x;
    int start = base_blk[(size_t)b * NBLK];
    int end   = base_blk[(size_t)(b + 1) * NBLK];
    cnt[tid] = 0; cnt[tid + 256] = 0;
    __syncthreads();
    for (int e = start + tid; e < end; e += 256) {
        int pk = epk[e];
        if (pk >= 0) atomicAdd(&cnt[pk >> 18], 1);
    }
    __syncthreads();
    int pairSum = cnt[2 * tid] + cnt[2 * tid + 1];
    ps[tid] = pairSum;
    __syncthreads();
#pragma unroll
    for (int o = 1; o < 256; o <<= 1) {
        int v = (tid >= o) ? ps[tid - o] : 0;
        __syncthreads();
        ps[tid] += v;
        __syncthreads();
    }
    int incl = ps[tid];
    off[2 * tid]     = incl - pairSum;
    off[2 * tid + 1] = incl - pairSum + cnt[2 * tid];
    __syncthreads();
    int nbase = b << BSH;
#pragma unroll
    for (int l = tid; l < BSZ; l += 256) {
        int node = nbase + l;
        if (node < n) {
            row_off[node] = start + off[l];
            degi[node]    = cnt[l];
            dinv[node]    = rsqrtf((float)cnt[l] + 1.0f);
        }
    }
    __syncthreads();
    for (int e = start + tid; e < end; e += 256) {
        int pk = epk[e];
        if (pk < 0) continue;
        int l = pk >> 18;
        int pos = atomicAdd(&off[l], 1);
        csr[start + pos] = pk & 0x3FFFF;
    }
}

// h = x @ W1 (9->16); hs = h * dinv
__global__ __launch_bounds__(256) void k_lin1(const float* __restrict__ x,
                                              const float* __restrict__ W1,
                                              const float* __restrict__ dinv,
                                              float* __restrict__ hs, int n)
{
    __shared__ float sW[144];
    if (threadIdx.x < 144) sW[threadIdx.x] = W1[threadIdx.x];
    __syncthreads();
    int i = blockIdx.x * 256 + threadIdx.x;
    if (i >= n) return;
    float xv[9];
#pragma unroll
    for (int k = 0; k < 9; ++k) xv[k] = x[(size_t)i * 9 + k];
    float di = dinv[i];
#pragma unroll
    for (int j = 0; j < 16; ++j) {
        float acc = 0.f;
#pragma unroll
        for (int k = 0; k < 9; ++k) acc = fmaf(xv[k], sW[k * 16 + j], acc);
        hs[(size_t)i * 16 + j] = acc * di;
    }
}

// One wave per node, 16 edge-slots x 4 lanes (float4, 2-way unrolled).
// Butterfly reduce leaves every lane with the full agg quarter set.
// MODE 0: out = agg = dinv*(hs_self + sum hs[src])                  [row f32x16]
// MODE 1: fused lin: out = (relu(agg + bias) @ W16x16) * dinv       [row f32x16]
template<int MODE>
__global__ __launch_bounds__(256) void k_gatherF(const int* __restrict__ csr,
                                                 const int* __restrict__ row_off,
                                                 const int* __restrict__ degi,
                                                 const float* __restrict__ dinv,
                                                 const float* __restrict__ hs,
                                                 const float* __restrict__ W,
                                                 const float* __restrict__ bias,
                                                 float* __restrict__ outb, int n)
{
    int wid = (int)(((long long)blockIdx.x * 256 + threadIdx.x) >> 6);
    if (wid >= n) return;
    int lane = threadIdx.x & 63;
    int slot = lane >> 2;          // 16 slots
    int q    = lane & 3;           // float4 quarter of the 16-feature row
    int start = row_off[wid];
    int deg   = degi[wid];
    float di  = dinv[wid];
    float4 sum;
    if (slot == 0) sum = *(const float4*)&hs[(size_t)wid * 16 + q * 4]; // self loop
    else           sum = make_float4(0.f, 0.f, 0.f, 0.f);
    int e = slot;
    for (; e + 16 < deg; e += 32) {                    // 2 lines in flight/lane
        int s0 = csr[start + e];
        int s1 = csr[start + e + 16];
        float4 v0 = *(const float4*)&hs[(size_t)s0 * 16 + q * 4];
        float4 v1 = *(const float4*)&hs[(size_t)s1 * 16 + q * 4];
        sum.x += v0.x + v1.x; sum.y += v0.y + v1.y;
        sum.z += v0.z + v1.z; sum.w += v0.w + v1.w;
    }
    if (e < deg) {
        int s0 = csr[start + e];
        float4 v0 = *(const float4*)&hs[(size_t)s0 * 16 + q * 4];
        sum.x += v0.x; sum.y += v0.y; sum.z += v0.z; sum.w += v0.w;
    }
#pragma unroll
    for (int off = 4; off < 64; off <<= 1) {
        sum.x += __shfl_xor(sum.x, off);
        sum.y += __shfl_xor(sum.y, off);
        sum.z += __shfl_xor(sum.z, off);
        sum.w += __shfl_xor(sum.w, off);
    }
    // agg quarter (valid in every lane): features q*4 .. q*4+3
    float4 aq = make_float4(sum.x * di, sum.y * di, sum.z * di, sum.w * di);

    if (MODE == 0) {
        if (slot == 0) *(float4*)&outb[(size_t)wid * 16 + q * 4] = aq;
    } else {
        // assemble full t = relu(agg + bias) in every lane via shuffles
        float t[16];
#pragma unroll
        for (int a = 0; a < 4; ++a) {
            t[4 * a + 0] = __shfl(aq.x, a);
            t[4 * a + 1] = __shfl(aq.y, a);
            t[4 * a + 2] = __shfl(aq.z, a);
            t[4 * a + 3] = __shfl(aq.w, a);
        }
#pragma unroll
        for (int k = 0; k < 16; ++k) {
            float v = t[k] + bias[k];
            t[k] = v > 0.f ? v : 0.f;
        }
        int j = lane & 15;
        float o = 0.f;
#pragma unroll
        for (int k = 0; k < 16; ++k)
            o = fmaf(t[k], W[k * 16 + j], o);
        if (lane < 16) outb[(size_t)wid * 16 + j] = o * di;
    }
}

// MLP head: feat=[x(9),relu(agg3+b3)(16)]; z=relu(feat@Wl2+bl2);
// z2=relu(z@Wl3+bl3); out=z2@Wl4+bl4. 4 waves/block, 16-node tile per wave.
// zs[4][16][128] (32KB -> 5 blocks/CU): feats staged in cols 0..24 (consumed
// before z is written, wave-lockstep); z stored with XOR swizzle
// col^=(row>>2)<<3 -> conflict-free float4 reads across the 4 ng rows.
// Plain launch_bounds(256): min-waves arg forces 64-VGPR cap + spills.
__global__ __launch_bounds__(256) void k_mlp(const float* __restrict__ x,
                                             const float* __restrict__ agg3,
                                             const float* __restrict__ b3,
                                             const float* __restrict__ Wl2,
                                             const float* __restrict__ bl2,
                                             const float* __restrict__ Wl3,
                                             const float* __restrict__ bl3,
                                             const float* __restrict__ Wl4,
                                             const float* __restrict__ bl4,
                                             float* __restrict__ out, int n)
{
    __shared__ __align__(16) float zs[4][16][128];   // 32768 B exactly

    int tid  = threadIdx.x;
    int w    = tid >> 6;
    int lane = tid & 63;
    int og   = lane & 15;
    int ng   = lane >> 4;
    int base = (blockIdx.x * 4 + w) * 16;

    // stage features (cols 0..24 of this wave's zs region)
    for (int idx = lane; idx < 16 * 25; idx += 64) {
        int nn = idx / 25, f = idx - nn * 25;
        int node = base + nn;
        float v = 0.f;
        if (node < n) {
            if (f < 9) v = x[(size_t)node * 9 + f];
            else {
                float t = agg3[(size_t)node * 16 + (f - 9)] + b3[f - 9];
                v = t > 0.f ? t : 0.f;
            }
        }
        zs[w][nn][f] = v;
    }
    __syncthreads();

    float acc[4][8];
    // ---- layer l2: feat[16][25] @ Wl2[25][128] ----
    {
        float4 b0 = *(const float4*)&bl2[og * 8];
        float4 b1 = *(const float4*)&bl2[og * 8 + 4];
#pragma unroll
        for (int i = 0; i < 4; ++i) {
            acc[i][0] = b0.x; acc[i][1] = b0.y; acc[i][2] = b0.z; acc[i][3] = b0.w;
            acc[i][4] = b1.x; acc[i][5] = b1.y; acc[i][6] = b1.z; acc[i][7] = b1.w;
        }
    }
#pragma unroll
    for (int k = 0; k < 25; ++k) {
        float4 w0 = *(const float4*)&Wl2[k * 128 + og * 8];
        float4 w1 = *(const float4*)&Wl2[k * 128 + og * 8 + 4];
#pragma unroll
        for (int i = 0; i < 4; ++i) {
            float f = zs[w][ng * 4 + i][k];
            acc[i][0] = fmaf(f, w0.x, acc[i][0]); acc[i][1] = fmaf(f, w0.y, acc[i][1]);
            acc[i][2] = fmaf(f, w0.z, acc[i][2]); acc[i][3] = fmaf(f, w0.w, acc[i][3]);
            acc[i][4] = fmaf(f, w1.x, acc[i][4]); acc[i][5] = fmaf(f, w1.y, acc[i][5]);
            acc[i][6] = fmaf(f, w1.z, acc[i][6]); acc[i][7] = fmaf(f, w1.w, acc[i][7]);
        }
    }
    __syncthreads();   // all feat reads done before z overwrites (cross-wave safe)
    {
        int c0 = (og * 8) ^ (ng << 3);               // swizzled column base
#pragma unroll
        for (int i = 0; i < 4; ++i) {
            float4 lo, hi;
            lo.x = acc[i][0] > 0.f ? acc[i][0] : 0.f; lo.y = acc[i][1] > 0.f ? acc[i][1] : 0.f;
            lo.z = acc[i][2] > 0.f ? acc[i][2] : 0.f; lo.w = acc[i][3] > 0.f ? acc[i][3] : 0.f;
            hi.x = acc[i][4] > 0.f ? acc[i][4] : 0.f; hi.y = acc[i][5] > 0.f ? acc[i][5] : 0.f;
            hi.z = acc[i][6] > 0.f ? acc[i][6] : 0.f; hi.w = acc[i][7] > 0.f ? acc[i][7] : 0.f;
            *(float4*)&zs[w][ng * 4 + i][c0]     = lo;
            *(float4*)&zs[w][ng * 4 + i][c0 + 4] = hi;
        }
    }
    __syncthreads();

    // ---- layer l3: z[16][128] @ Wl3[128][128], k-blocked by 4 ----
    {
        float4 b0 = *(const float4*)&bl3[og * 8];
        float4 b1 = *(const float4*)&bl3[og * 8 + 4];
#pragma unroll
        for (int i = 0; i < 4; ++i) {
            acc[i][0] = b0.x; acc[i][1] = b0.y; acc[i][2] = b0.z; acc[i][3] = b0.w;
            acc[i][4] = b1.x; acc[i][5] = b1.y; acc[i][6] = b1.z; acc[i][7] = b1.w;
        }
    }
    int swz = ng << 3;
#pragma unroll 2
    for (int k4 = 0; k4 < 64; k4 += 4) {
        float4 z4[4];
#pragma unroll
        for (int i = 0; i < 4; ++i)
            z4[i] = *(const float4*)&zs[w][ng * 4 + i][k4 ^ swz];
#pragma unroll
        for (int kk = 0; kk < 4; ++kk) {
            const float* wr = &Wl3[(k4 + kk) * 128 + og * 8];
            float4 w0 = *(const float4*)wr;
            float4 w1 = *(const float4*)(wr + 4);
#pragma unroll
            for (int i = 0; i < 4; ++i) {
                float zz = (kk == 0) ? z4[i].x : (kk == 1) ? z4[i].y
                         : (kk == 2) ? z4[i].z : z4[i].w;
                acc[i][0] = fmaf(zz, w0.x, acc[i][0]); acc[i][1] = fmaf(zz, w0.y, acc[i][1]);
                acc[i][2] = fmaf(zz, w0.z, acc[i][2]); acc[i][3] = fmaf(zz, w0.w, acc[i][3]);
                acc[i][4] = fmaf(zz, w1.x, acc[i][4]); acc[i][5] = fmaf(zz, w1.y, acc[i][5]);
                acc[i][6] = fmaf(zz, w1.z, acc[i][6]); acc[i][7] = fmaf(zz, w1.w, acc[i][7]);
            }
        }
    }
    __syncthreads();    // keep all waves on the same 32KB half of Wl3 (L1)
#pragma unroll 2
    for (int k4 = 64; k4 < 128; k4 += 4) {
        float4 z4[4];
#pragma unroll
        for (int i = 0; i < 4; ++i)
            z4[i] = *(const float4*)&zs[w][ng * 4 + i][k4 ^ swz];
#pragma unroll
        for (int kk = 0; kk < 4; ++kk) {
            const float* wr = &Wl3[(k4 + kk) * 128 + og * 8];
            float4 w0 = *(const float4*)wr;
            float4 w1 = *(const float4*)(wr + 4);
#pragma unroll
            for (int i = 0; i < 4; ++i) {
                float zz = (kk == 0) ? z4[i].x : (kk == 1) ? z4[i].y
                         : (kk == 2) ? z4[i].z : z4[i].w;
                acc[i][0] = fmaf(zz, w0.x, acc[i][0]); acc[i][1] = fmaf(zz, w0.y, acc[i][1]);
                acc[i][2] = fmaf(zz, w0.z, acc[i][2]); acc[i][3] = fmaf(zz, w0.w, acc[i][3]);
                acc[i][4] = fmaf(zz, w1.x, acc[i][4]); acc[i][5] = fmaf(zz, w1.y, acc[i][5]);
                acc[i][6] = fmaf(zz, w1.z, acc[i][6]); acc[i][7] = fmaf(zz, w1.w, acc[i][7]);
            }
        }
    }

    // ---- layer l4: relu, dot with Wl4, reduce over og ----
    {
        float4 w40 = *(const float4*)&Wl4[og * 8];
        float4 w41 = *(const float4*)&Wl4[og * 8 + 4];
        float bb = bl4[0];
#pragma unroll
        for (int i = 0; i < 4; ++i) {
            float p = 0.f;
            p = fmaf(acc[i][0] > 0.f ? acc[i][0] : 0.f, w40.x, p);
            p = fmaf(acc[i][1] > 0.f ? acc[i][1] : 0.f, w40.y, p);
            p = fmaf(acc[i][2] > 0.f ? acc[i][2] : 0.f, w40.z, p);
            p = fmaf(acc[i][3] > 0.f ? acc[i][3] : 0.f, w40.w, p);
            p = fmaf(acc[i][4] > 0.f ? acc[i][4] : 0.f, w41.x, p);
            p = fmaf(acc[i][5] > 0.f ? acc[i][5] : 0.f, w41.y, p);
            p = fmaf(acc[i][6] > 0.f ? acc[i][6] : 0.f, w41.z, p);
            p = fmaf(acc[i][7] > 0.f ? acc[i][7] : 0.f, w41.w, p);
            p += __shfl_xor(p, 1);
            p += __shfl_xor(p, 2);
            p += __shfl_xor(p, 4);
            p += __shfl_xor(p, 8);
            int node = base + ng * 4 + i;
            if (og == 0 && node < n) out[node] = p + bb;
        }
    }
}

extern "C" void kernel_launch(void* const* d_in, const int* in_sizes, int n_in,
                              void* d_out, int out_size, void* d_ws, size_t ws_size,
                              hipStream_t stream)
{
    const float* x   = (const float*)d_in[0];
    const void*  ei  = d_in[1];
    const float* W1  = (const float*)d_in[2];
    const float* b1  = (const float*)d_in[3];
    const float* W2  = (const float*)d_in[4];
    const float* b2  = (const float*)d_in[5];
    const float* W3  = (const float*)d_in[6];
    const float* b3  = (const float*)d_in[7];
    const float* Wl2 = (const float*)d_in[8];
    const float* bl2 = (const float*)d_in[9];
    const float* Wl3 = (const float*)d_in[10];
    const float* bl3 = (const float*)d_in[11];
    const float* Wl4 = (const float*)d_in[12];
    const float* bl4 = (const float*)d_in[13];
    float* out = (float*)d_out;

    int n        = in_sizes[0] / 9;          // 250000
    long long e2 = (long long)in_sizes[1];   // 2*E
    long long E  = e2 / 2;
    int NB       = (n + BSZ - 1) >> BSH;     // 489 buckets
    int L        = NB * NBLK + 1;            // scan length (extra slot = total)
    size_t EPAD  = (size_t)E + (size_t)NBLK * NB * 16;   // binned region elems

    char* ws = (char*)d_ws;
    size_t off = 0;
    int*   flag     = (int*)(ws + off); off += 256;
    int*   cnt_blk  = (int*)(ws + off); off += (size_t)L * 4;        off = (off + 255) & ~(size_t)255;
    int*   base_blk = (int*)(ws + off); off += (size_t)L * 4;        off = (off + 255) & ~(size_t)255;
    int*   partials = (int*)(ws + off); off += 16384;
    float* dinv     = (float*)(ws + off); off += (size_t)n * 4;      off = (off + 255) & ~(size_t)255;
    int*   degi     = (int*)(ws + off); off += (size_t)n * 4;        off = (off + 255) & ~(size_t)255;
    int*   row_off  = (int*)(ws + off); off += (size_t)n * 4;        off = (off + 255) & ~(size_t)255;
    int*   csr      = (int*)(ws + off); off += EPAD * 4;             off = (off + 255) & ~(size_t)255;
    int*   epk      = (int*)(ws + off); off += EPAD * 4;             off = (off + 255) & ~(size_t)255;
    // bufA/bufB alias epk (dead after k_csr); EPAD*4 = 36 MB >= 32 MB needed
    float* bufA = (float*)epk;
    float* bufB = bufA + (size_t)n * 16;

    int nb_n = (n + 255) / 256;
    int nb_s = (L + 255) / 256;

    k_detect<<<1, 64, 0, stream>>>(ei, flag, n);
    hipMemsetAsync(cnt_blk + (L - 1), 0, 4, stream);   // extra slot -> total
    k_hist2<<<NBLK, 256, 0, stream>>>(ei, flag, cnt_blk, E, NB);
    k_scan1<<<nb_s, 256, 0, stream>>>(cnt_blk, base_blk, partials, L);
    k_scan2<<<1, 1024, 0, stream>>>(partials, nb_s);
    k_scan3<<<nb_s, 256, 0, stream>>>(base_blk, partials, L);
    k_bin<<<NBLK, 256, 0, stream>>>(ei, flag, base_blk, epk, E, NB);
    k_csr<<<NB, 256, 0, stream>>>(epk, base_blk, csr, row_off, degi, dinv, n);

    int nb_g = (n + 3) / 4;   // one wave per node, 4 waves/block
    // layer 1 transform
    k_lin1<<<nb_n, 256, 0, stream>>>(x, W1, dinv, bufA, n);
    // gather1 + fused lin2:  bufA -> bufB
    k_gatherF<1><<<nb_g, 256, 0, stream>>>(csr, row_off, degi, dinv, bufA, W2, b1,
                                           bufB, n);
    // gather2 + fused lin3:  bufB -> bufA
    k_gatherF<1><<<nb_g, 256, 0, stream>>>(csr, row_off, degi, dinv, bufB, W3, b2,
                                           bufA, n);
    // gather3 (plain agg):   bufA -> bufB
    k_gatherF<0><<<nb_g, 256, 0, stream>>>(csr, row_off, degi, dinv, bufA, nullptr,
                                           nullptr, bufB, n);
    // MLP head
    k_mlp<<<(n + 63) / 64, 256, 0, stream>>>(x, bufB, b3, Wl2, bl2, Wl3, bl3, Wl4, bl4,
                                             out, n);
}

// Round 10
// 522.330 us; speedup vs baseline: 4.4899x; 1.1359x over previous
//
#include <hip/hip_runtime.h>

// ---------------------------------------------------------------------------
// GCN: 3x GCNConv(9->16->16->16) + MLP(concat 25 ->128->128->1), N=250000,
// E=5,000,000 edges + self loops. f32 in/out; edge_index int32 OR int64
// (detected on device).
// Pipeline: deterministic 2-pass binning into 512-node buckets (single-writer
// 64B lines, zero global atomics) -> within-bucket counting sort to exact CSR
// (fused deg/dinv) -> per-node wave gather with FUSED 16x16 linear epilogue
// (shuffle-GEMV) -> bf16 MFMA MLP head (16x16x32, fp32 accumulate).
// NOTE: k_mlp uses plain __launch_bounds__(256): any min-waves second arg
// makes the allocator cap at 64 VGPRs and spill the acc tile to scratch
// (observed r2/r5/r6: 190MB scratch traffic, 2-3x slowdown).
// ---------------------------------------------------------------------------

#define NBLK 512          // binning blocks (each owns a contiguous edge chunk)
#define BSH  9            // bucket shift: 512 nodes per bucket
#define BSZ  512
#define MAXNB 1024        // max buckets supported (n <= 524288)

typedef __attribute__((ext_vector_type(8))) __bf16 bf16x8;
typedef __attribute__((ext_vector_type(4))) float  f32x4;

__device__ __forceinline__ unsigned short f2b(float f)   // f32 -> bf16 RNE
{
    unsigned u = __float_as_uint(f);
    unsigned r = (u + 0x7FFFu + ((u >> 16) & 1u)) >> 16;
    return (unsigned short)r;
}

__global__ __launch_bounds__(64) void k_detect(const void* __restrict__ edges,
                                               int* __restrict__ flag, int n_nodes)
{
    if (threadIdx.x == 0 && blockIdx.x == 0) {
        const long long* p = (const long long*)edges;
        int is64 = 1;
        for (int i = 0; i < 16; ++i) {
            long long v = p[i];
            if (v < 0 || v >= (long long)n_nodes) is64 = 0;
        }
        *flag = is64;
    }
}

// little-endian: low 32 bits of int64 value < 2^31 equal the int32 value
__device__ __forceinline__ int ld_idx(const void* edges, int f64, long long idx)
{
    return f64 ? ((const int*)edges)[idx << 1] : ((const int*)edges)[idx];
}

// per-block bucket histogram of dst; write rounded-to-16 counts bucket-major
__global__ __launch_bounds__(256) void k_hist2(const void* __restrict__ edges,
                                               const int* __restrict__ flag,
                                               int* __restrict__ cnt_blk,
                                               long long E, int NB)
{
    __shared__ int cnt[MAXNB];
    int tid = threadIdx.x;
    for (int b = tid; b < NB; b += 256) cnt[b] = 0;
    __syncthreads();
    int f64 = *flag;
    long long chunk = (E + NBLK - 1) / NBLK;
    long long lo = (long long)blockIdx.x * chunk;
    long long hi = lo + chunk; if (hi > E) hi = E;
    for (long long i = lo + tid; i < hi; i += 256) {
        int d = ld_idx(edges, f64, E + i);
        atomicAdd(&cnt[d >> BSH], 1);
    }
    __syncthreads();
    for (int b = tid; b < NB; b += 256)
        cnt_blk[(size_t)b * NBLK + blockIdx.x] = (cnt[b] + 15) & ~15;
}

// exclusive scan stage 1
__global__ __launch_bounds__(256) void k_scan1(const int* __restrict__ in,
                                               int* __restrict__ excl,
                                               int* __restrict__ partials, int n)
{
    __shared__ int s[256];
    int tid = threadIdx.x;
    int i = blockIdx.x * 256 + tid;
    int v = (i < n) ? in[i] : 0;
    s[tid] = v;
    __syncthreads();
#pragma unroll
    for (int off = 1; off < 256; off <<= 1) {
        int t = (tid >= off) ? s[tid - off] : 0;
        __syncthreads();
        s[tid] += t;
        __syncthreads();
    }
    if (i < n) excl[i] = s[tid] - v;
    if (tid == 255) partials[blockIdx.x] = s[255];
}

// stage 2: single block, exclusive scan of partials (carry loop)
__global__ __launch_bounds__(1024) void k_scan2(int* __restrict__ p, int nb)
{
    __shared__ int s[1024];
    __shared__ int carry_s;
    int t = threadIdx.x;
    if (t == 0) carry_s = 0;
    __syncthreads();
    for (int base = 0; base < nb; base += 1024) {
        int idx = base + t;
        int v = (idx < nb) ? p[idx] : 0;
        s[t] = v;
        __syncthreads();
        for (int off = 1; off < 1024; off <<= 1) {
            int u = (t >= off) ? s[t - off] : 0;
            __syncthreads();
            s[t] += u;
            __syncthreads();
        }
        int carry = carry_s;
        if (idx < nb) p[idx] = carry + s[t] - v;
        __syncthreads();
        if (t == 0) carry_s += s[1023];
        __syncthreads();
    }
}

// stage 3: add block offsets
__global__ __launch_bounds__(256) void k_scan3(int* __restrict__ excl,
                                               const int* __restrict__ partials, int n)
{
    int i = blockIdx.x * 256 + threadIdx.x;
    if (i < n) excl[i] += partials[blockIdx.x];
}

// re-histogram own chunk, scatter packed edges into own 64B-aligned regions;
// sentinel-fill pad. Zero global atomics.
__global__ __launch_bounds__(256) void k_bin(const void* __restrict__ edges,
                                             const int* __restrict__ flag,
                                             const int* __restrict__ base_blk,
                                             int* __restrict__ epk,
                                             long long E, int NB)
{
    __shared__ int cnt[MAXNB];
    __shared__ int base[MAXNB];
    __shared__ int cur[MAXNB];
    int tid = threadIdx.x;
    for (int b = tid; b < NB; b += 256) cnt[b] = 0;
    __syncthreads();
    int f64 = *flag;
    long long chunk = (E + NBLK - 1) / NBLK;
    long long lo = (long long)blockIdx.x * chunk;
    long long hi = lo + chunk; if (hi > E) hi = E;
    for (long long i = lo + tid; i < hi; i += 256) {
        int d = ld_idx(edges, f64, E + i);
        atomicAdd(&cnt[d >> BSH], 1);
    }
    __syncthreads();
    for (int b = tid; b < NB; b += 256) {
        base[b] = base_blk[(size_t)b * NBLK + blockIdx.x];
        cur[b] = 0;
    }
    __syncthreads();
    for (long long i = lo + tid; i < hi; i += 256) {
        int s = ld_idx(edges, f64, i);
        int d = ld_idx(edges, f64, E + i);
        int b = d >> BSH;
        int slot = atomicAdd(&cur[b], 1);
        epk[base[b] + slot] = ((d & (BSZ - 1)) << 18) | s;
    }
    __syncthreads();
    for (int b = tid; b < NB; b += 256) {
        int c = cnt[b];
        int r = (c + 15) & ~15;
        for (int j = c; j < r; ++j) epk[base[b] + j] = -1;
    }
}

// within-bucket counting sort -> exact CSR; fused deg/dinv/row_off.
__global__ __launch_bounds__(256) void k_csr(const int* __restrict__ epk,
                                             const int* __restrict__ base_blk,
                                             int* __restrict__ csr,
                                             int* __restrict__ row_off,
                                             int* __restrict__ degi,
                                             float* __restrict__ dinv, int n)
{
    __shared__ int cnt[BSZ];
    __shared__ int off[BSZ];
    __shared__ int ps[256];
    int b = blockIdx.x;
    int tid = threadIdx.x;
    int start = base_blk[(size_t)b * NBLK];
    int end   = base_blk[(size_t)(b + 1) * NBLK];
    cnt[tid] = 0; cnt[tid + 256] = 0;
    __syncthreads();
    for (int e = start + tid; e < end; e += 256) {
        int pk = epk[e];
        if (pk >= 0) atomicAdd(&cnt[pk >> 18], 1);
    }
    __syncthreads();
    int pairSum = cnt[2 * tid] + cnt[2 * tid + 1];
    ps[tid] = pairSum;
    __syncthreads();
#pragma unroll
    for (int o = 1; o < 256; o <<= 1) {
        int v = (tid >= o) ? ps[tid - o] : 0;
        __syncthreads();
        ps[tid] += v;
        __syncthreads();
    }
    int incl = ps[tid];
    off[2 * tid]     = incl - pairSum;
    off[2 * tid + 1] = incl - pairSum + cnt[2 * tid];
    __syncthreads();
    int nbase = b << BSH;
#pragma unroll
    for (int l = tid; l < BSZ; l += 256) {
        int node = nbase + l;
        if (node < n) {
            row_off[node] = start + off[l];
            degi[node]    = cnt[l];
            dinv[node]    = rsqrtf((float)cnt[l] + 1.0f);
        }
    }
    __syncthreads();
    for (int e = start + tid; e < end; e += 256) {
        int pk = epk[e];
        if (pk < 0) continue;
        int l = pk >> 18;
        int pos = atomicAdd(&off[l], 1);
        csr[start + pos] = pk & 0x3FFFF;
    }
}

// h = x @ W1 (9->16); hs = h * dinv
__global__ __launch_bounds__(256) void k_lin1(const float* __restrict__ x,
                                              const float* __restrict__ W1,
                                              const float* __restrict__ dinv,
                                              float* __restrict__ hs, int n)
{
    __shared__ float sW[144];
    if (threadIdx.x < 144) sW[threadIdx.x] = W1[threadIdx.x];
    __syncthreads();
    int i = blockIdx.x * 256 + threadIdx.x;
    if (i >= n) return;
    float xv[9];
#pragma unroll
    for (int k = 0; k < 9; ++k) xv[k] = x[(size_t)i * 9 + k];
    float di = dinv[i];
#pragma unroll
    for (int j = 0; j < 16; ++j) {
        float acc = 0.f;
#pragma unroll
        for (int k = 0; k < 9; ++k) acc = fmaf(xv[k], sW[k * 16 + j], acc);
        hs[(size_t)i * 16 + j] = acc * di;
    }
}

// One wave per node, 16 edge-slots x 4 lanes (float4, 2-way unrolled).
// MODE 0: out = agg = dinv*(hs_self + sum hs[src])
// MODE 1: fused lin: out = (relu(agg + bias) @ W16x16) * dinv
template<int MODE>
__global__ __launch_bounds__(256) void k_gatherF(const int* __restrict__ csr,
                                                 const int* __restrict__ row_off,
                                                 const int* __restrict__ degi,
                                                 const float* __restrict__ dinv,
                                                 const float* __restrict__ hs,
                                                 const float* __restrict__ W,
                                                 const float* __restrict__ bias,
                                                 float* __restrict__ outb, int n)
{
    int wid = (int)(((long long)blockIdx.x * 256 + threadIdx.x) >> 6);
    if (wid >= n) return;
    int lane = threadIdx.x & 63;
    int slot = lane >> 2;          // 16 slots
    int q    = lane & 3;           // float4 quarter of the 16-feature row
    int start = row_off[wid];
    int deg   = degi[wid];
    float di  = dinv[wid];
    float4 sum;
    if (slot == 0) sum = *(const float4*)&hs[(size_t)wid * 16 + q * 4]; // self loop
    else           sum = make_float4(0.f, 0.f, 0.f, 0.f);
    int e = slot;
    for (; e + 16 < deg; e += 32) {                    // 2 lines in flight/lane
        int s0 = csr[start + e];
        int s1 = csr[start + e + 16];
        float4 v0 = *(const float4*)&hs[(size_t)s0 * 16 + q * 4];
        float4 v1 = *(const float4*)&hs[(size_t)s1 * 16 + q * 4];
        sum.x += v0.x + v1.x; sum.y += v0.y + v1.y;
        sum.z += v0.z + v1.z; sum.w += v0.w + v1.w;
    }
    if (e < deg) {
        int s0 = csr[start + e];
        float4 v0 = *(const float4*)&hs[(size_t)s0 * 16 + q * 4];
        sum.x += v0.x; sum.y += v0.y; sum.z += v0.z; sum.w += v0.w;
    }
#pragma unroll
    for (int off = 4; off < 64; off <<= 1) {
        sum.x += __shfl_xor(sum.x, off);
        sum.y += __shfl_xor(sum.y, off);
        sum.z += __shfl_xor(sum.z, off);
        sum.w += __shfl_xor(sum.w, off);
    }
    float4 aq = make_float4(sum.x * di, sum.y * di, sum.z * di, sum.w * di);

    if (MODE == 0) {
        if (slot == 0) *(float4*)&outb[(size_t)wid * 16 + q * 4] = aq;
    } else {
        float t[16];
#pragma unroll
        for (int a = 0; a < 4; ++a) {
            t[4 * a + 0] = __shfl(aq.x, a);
            t[4 * a + 1] = __shfl(aq.y, a);
            t[4 * a + 2] = __shfl(aq.z, a);
            t[4 * a + 3] = __shfl(aq.w, a);
        }
#pragma unroll
        for (int k = 0; k < 16; ++k) {
            float v = t[k] + bias[k];
            t[k] = v > 0.f ? v : 0.f;
        }
        int j = lane & 15;
        float o = 0.f;
#pragma unroll
        for (int k = 0; k < 16; ++k)
            o = fmaf(t[k], W[k * 16 + j], o);
        if (lane < 16) outb[(size_t)wid * 16 + j] = o * di;
    }
}

// convert + transpose MLP weights to bf16: Wl2T[128 col][32 k] (k>=25 zero),
// Wl3T[128 col][128 k]
__global__ __launch_bounds__(256) void k_cvt(const float* __restrict__ Wl2,
                                             const float* __restrict__ Wl3,
                                             unsigned short* __restrict__ Wl2T,
                                             unsigned short* __restrict__ Wl3T)
{
    int i = blockIdx.x * 256 + threadIdx.x;
    if (i < 128 * 32) {
        int c = i >> 5, k = i & 31;
        float v = (k < 25) ? Wl2[k * 128 + c] : 0.f;
        Wl2T[i] = f2b(v);
    }
    int j = i - 128 * 32;
    if (j >= 0 && j < 128 * 128) {
        int c = j >> 7, k = j & 127;
        Wl3T[j] = f2b(Wl3[k * 128 + c]);
    }
}

// MLP head on matrix cores (bf16 in, fp32 accumulate):
// feat=[x(9),relu(agg3+b3)(16)] pad32 bf16; z=relu(feat@Wl2+bl2) bf16 in LDS
// (XOR swizzle byte^=(row&7)<<4 on 256B rows -> conflict-free A-frag reads);
// z2=relu(z@Wl3+bl3); out=z2@Wl4+bl4 (f32 epilogue).
// 4 waves/block, 16 nodes/wave. mfma_f32_16x16x32_bf16:
//   A: [m=lane&15][k=8*(lane>>4)+j]; B: [k=8*(lane>>4)+j][n=lane&15];
//   D: [m=(lane>>4)*4+r][n=lane&15]   (C/D verified layout, m89)
__global__ __launch_bounds__(256) void k_mlp(const float* __restrict__ x,
                                             const float* __restrict__ agg3,
                                             const float* __restrict__ b3,
                                             const unsigned short* __restrict__ Wl2T,
                                             const float* __restrict__ bl2,
                                             const unsigned short* __restrict__ Wl3T,
                                             const float* __restrict__ bl3,
                                             const float* __restrict__ Wl4,
                                             const float* __restrict__ bl4,
                                             float* __restrict__ out, int n)
{
    __shared__ __align__(16) unsigned short featb[4][16 * 40];  // stride 40 (80B)
    __shared__ __align__(16) unsigned short zb[4][16 * 128];    // 256B rows, swizzled

    int tid  = threadIdx.x;
    int w    = tid >> 6;
    int lane = tid & 63;
    int g    = lane >> 4;      // 0..3
    int l15  = lane & 15;
    int base = (blockIdx.x * 4 + w) * 16;

    // stage feat bf16 [16][32] (cols 25..31 zero)
    for (int idx = lane; idx < 16 * 32; idx += 64) {
        int nn = idx >> 5, f = idx & 31;
        int node = base + nn;
        float v = 0.f;
        if (node < n) {
            if (f < 9) v = x[(size_t)node * 9 + f];
            else if (f < 25) {
                float t = agg3[(size_t)node * 16 + (f - 9)] + b3[f - 9];
                v = t > 0.f ? t : 0.f;
            }
        }
        featb[w][nn * 40 + f] = f2b(v);
    }
    __syncthreads();

    // ---- layer l2: z[16][128] = relu(feat @ Wl2 + bl2), one K=32 MFMA/tile ----
    bf16x8 a2 = *(const bf16x8*)&featb[w][l15 * 40 + 8 * g];
    char* zbw = (char*)&zb[w][0];
#pragma unroll
    for (int t = 0; t < 8; ++t) {
        int col = l15 + 16 * t;
        bf16x8 b2 = *(const bf16x8*)&Wl2T[(size_t)col * 32 + 8 * g];
        f32x4 c = {0.f, 0.f, 0.f, 0.f};
        c = __builtin_amdgcn_mfma_f32_16x16x32_bf16(a2, b2, c, 0, 0, 0);
        float bb = bl2[col];
#pragma unroll
        for (int r = 0; r < 4; ++r) {
            int node = g * 4 + r;
            float v = c[r] + bb;
            v = v > 0.f ? v : 0.f;
            int byte = node * 256 + ((2 * col) ^ ((node & 7) << 4));
            *(unsigned short*)(zbw + byte) = f2b(v);
        }
    }
    __syncthreads();

    // ---- layer l3: z[16][128] @ Wl3[128][128], 4 K-steps x 8 N-tiles ----
    f32x4 acc[8];
#pragma unroll
    for (int t = 0; t < 8; ++t) acc[t] = (f32x4){0.f, 0.f, 0.f, 0.f};
#pragma unroll
    for (int s = 0; s < 4; ++s) {
        int kb = 8 * g + 32 * s;
        int byteA = l15 * 256 + ((2 * kb) ^ ((l15 & 7) << 4));
        bf16x8 a3 = *(const bf16x8*)(zbw + byteA);
#pragma unroll
        for (int t = 0; t < 8; ++t) {
            bf16x8 b3f = *(const bf16x8*)&Wl3T[(size_t)(l15 + 16 * t) * 128 + kb];
            acc[t] = __builtin_amdgcn_mfma_f32_16x16x32_bf16(a3, b3f, acc[t], 0, 0, 0);
        }
    }

    // ---- layer l4: relu, dot with Wl4, reduce over the 16 n-lanes ----
    float p[4] = {0.f, 0.f, 0.f, 0.f};
#pragma unroll
    for (int t = 0; t < 8; ++t) {
        int col = l15 + 16 * t;
        float b3v = bl3[col];
        float w4  = Wl4[col];
#pragma unroll
        for (int r = 0; r < 4; ++r) {
            float v = acc[t][r] + b3v;
            v = v > 0.f ? v : 0.f;
            p[r] = fmaf(v, w4, p[r]);
        }
    }
    float bb = bl4[0];
#pragma unroll
    for (int r = 0; r < 4; ++r) {
        float s = p[r];
        s += __shfl_xor(s, 1);
        s += __shfl_xor(s, 2);
        s += __shfl_xor(s, 4);
        s += __shfl_xor(s, 8);
        int node = base + g * 4 + r;
        if (l15 == 0 && node < n) out[node] = s + bb;
    }
}

extern "C" void kernel_launch(void* const* d_in, const int* in_sizes, int n_in,
                              void* d_out, int out_size, void* d_ws, size_t ws_size,
                              hipStream_t stream)
{
    const float* x   = (const float*)d_in[0];
    const void*  ei  = d_in[1];
    const float* W1  = (const float*)d_in[2];
    const float* b1  = (const float*)d_in[3];
    const float* W2  = (const float*)d_in[4];
    const float* b2  = (const float*)d_in[5];
    const float* W3  = (const float*)d_in[6];
    const float* b3  = (const float*)d_in[7];
    const float* Wl2 = (const float*)d_in[8];
    const float* bl2 = (const float*)d_in[9];
    const float* Wl3 = (const float*)d_in[10];
    const float* bl3 = (const float*)d_in[11];
    const float* Wl4 = (const float*)d_in[12];
    const float* bl4 = (const float*)d_in[13];
    float* out = (float*)d_out;

    int n        = in_sizes[0] / 9;          // 250000
    long long e2 = (long long)in_sizes[1];   // 2*E
    long long E  = e2 / 2;
    int NB       = (n + BSZ - 1) >> BSH;     // 489 buckets
    int L        = NB * NBLK + 1;            // scan length (extra slot = total)
    size_t EPAD  = (size_t)E + (size_t)NBLK * NB * 16;   // binned region elems

    char* ws = (char*)d_ws;
    size_t off = 0;
    int*   flag     = (int*)(ws + off); off += 256;
    int*   cnt_blk  = (int*)(ws + off); off += (size_t)L * 4;        off = (off + 255) & ~(size_t)255;
    int*   base_blk = (int*)(ws + off); off += (size_t)L * 4;        off = (off + 255) & ~(size_t)255;
    int*   partials = (int*)(ws + off); off += 16384;
    unsigned short* wl2t = (unsigned short*)(ws + off); off += 128 * 32 * 2;
    off = (off + 255) & ~(size_t)255;
    unsigned short* wl3t = (unsigned short*)(ws + off); off += 128 * 128 * 2;
    off = (off + 255) & ~(size_t)255;
    float* dinv     = (float*)(ws + off); off += (size_t)n * 4;      off = (off + 255) & ~(size_t)255;
    int*   degi     = (int*)(ws + off); off += (size_t)n * 4;        off = (off + 255) & ~(size_t)255;
    int*   row_off  = (int*)(ws + off); off += (size_t)n * 4;        off = (off + 255) & ~(size_t)255;
    int*   csr      = (int*)(ws + off); off += EPAD * 4;             off = (off + 255) & ~(size_t)255;
    int*   epk      = (int*)(ws + off); off += EPAD * 4;             off = (off + 255) & ~(size_t)255;
    // bufA/bufB alias epk (dead after k_csr); EPAD*4 = 36 MB >= 32 MB needed
    float* bufA = (float*)epk;
    float* bufB = bufA + (size_t)n * 16;

    int nb_n = (n + 255) / 256;
    int nb_s = (L + 255) / 256;

    k_detect<<<1, 64, 0, stream>>>(ei, flag, n);
    hipMemsetAsync(cnt_blk + (L - 1), 0, 4, stream);   // extra slot -> total
    k_cvt<<<80, 256, 0, stream>>>(Wl2, Wl3, wl2t, wl3t);
    k_hist2<<<NBLK, 256, 0, stream>>>(ei, flag, cnt_blk, E, NB);
    k_scan1<<<nb_s, 256, 0, stream>>>(cnt_blk, base_blk, partials, L);
    k_scan2<<<1, 1024, 0, stream>>>(partials, nb_s);
    k_scan3<<<nb_s, 256, 0, stream>>>(base_blk, partials, L);
    k_bin<<<NBLK, 256, 0, stream>>>(ei, flag, base_blk, epk, E, NB);
    k_csr<<<NB, 256, 0, stream>>>(epk, base_blk, csr, row_off, degi, dinv, n);

    int nb_g = (n + 3) / 4;   // one wave per node, 4 waves/block
    // layer 1 transform
    k_lin1<<<nb_n, 256, 0, stream>>>(x, W1, dinv, bufA, n);
    // gather1 + fused lin2:  bufA -> bufB
    k_gatherF<1><<<nb_g, 256, 0, stream>>>(csr, row_off, degi, dinv, bufA, W2, b1,
                                           bufB, n);
    // gather2 + fused lin3:  bufB -> bufA
    k_gatherF<1><<<nb_g, 256, 0, stream>>>(csr, row_off, degi, dinv, bufB, W3, b2,
                                           bufA, n);
    // gather3 (plain agg):   bufA -> bufB
    k_gatherF<0><<<nb_g, 256, 0, stream>>>(csr, row_off, degi, dinv, bufA, nullptr,
                                           nullptr, bufB, n);
    // MLP head (bf16 MFMA)
    k_mlp<<<(n + 63) / 64, 256, 0, stream>>>(x, bufB, b3, wl2t, bl2, wl3t, bl3,
                                             Wl4, bl4, out, n);
}